// Round 2
// baseline (1013.617 us; speedup 1.0000x reference)
//
#include <hip/hip_runtime.h>
#include <math.h>

#define NB 2
#define NN 256
#define FF 64
#define HH 64
#define NHEADS 4
#define KK 50
#define CC 256

constexpr int BN = NB * NN;          // 512
constexpr int NPAIR = NB * NN * NN;  // 131072

__device__ __forceinline__ float siluf(float v) { return v / (1.f + __expf(-v)); }
__device__ __forceinline__ float sigmoidf_(float v) { return 1.f / (1.f + __expf(-v)); }
__device__ __forceinline__ float tanh_fast(float x) {
    x = fminf(fmaxf(x, -15.f), 15.f);
    float e = __expf(2.f * x);
    return (e - 1.f) / (e + 1.f);
}

// ---------------------------------------------------------------------------
// K1: edge model. Block = 32 pairs sharing (b,i) (one j-tile). 256 threads.
// Thread owns 2 pairs (g = tid>>4 -> pairs 2g,2g+1) x 4 channels (c4 = (tid&15)*4).
// Weights via float4 global loads (L1-hot), inputs via ds_read_b128 broadcast.
// ---------------------------------------------------------------------------
__global__ __launch_bounds__(256) void k1_edge(
    const float* __restrict__ h, const float* __restrict__ x,
    const float* __restrict__ means, const float* __restrict__ betas,
    const float* __restrict__ W_in, const float* __restrict__ b_in,
    const float* __restrict__ W_o1, const float* __restrict__ b_o1,
    const float* __restrict__ W_o2, const float* __restrict__ b_o2,
    const float* __restrict__ Ws, const float* __restrict__ bs,
    float* __restrict__ he_mtx, float* __restrict__ sem_logit,
    float* __restrict__ norm_g)
{
    __shared__ float hj[32][68];      // j-tile h rows (pad 68 -> conflict-free b128; aliased as he later)
    __shared__ float s1[32][68];
    __shared__ float rbfhk[32][52];   // pad 52 (208B rows, 16B aligned)
    __shared__ float hi_s[64];
    __shared__ float nrm_s[32];
    __shared__ float en_s[32];

    const int tid = threadIdx.x;
    const int blk = blockIdx.x;          // 4096 blocks
    const int bi  = blk >> 3;            // b*N + i
    const int jt  = (blk & 7) * 32;
    const int b   = bi >> 8;
    const int i   = bi & 255;

    const int g  = tid >> 4;             // 0..15
    const int cq = tid & 15;
    const int c4 = cq * 4;
    const int p0 = 2 * g, p1 = 2 * g + 1;

    const float* hb = h + (size_t)b * NN * FF;
    const float* xb = x + (size_t)b * NN * 3;

    // ---- phase 0: stage h_j tile, h_i, norms
    {
        const float4* src = (const float4*)(hb + (size_t)jt * FF);
#pragma unroll
        for (int it = 0; it < 2; it++) {
            int idx = tid + it * 256;        // 512 float4s total
            float4 vv = src[idx];
            int r = idx >> 4;
            int c = (idx & 15) * 4;
            *(float4*)&hj[r][c] = vv;
        }
        if (tid < 16) ((float4*)hi_s)[tid] = ((const float4*)(hb + (size_t)i * FF))[tid];
        if (tid < 32) {
            int j = jt + tid;
            float dx0 = xb[j * 3 + 0] - xb[i * 3 + 0];
            float dx1 = xb[j * 3 + 1] - xb[i * 3 + 1];
            float dx2 = xb[j * 3 + 2] - xb[i * 3 + 2];
            float d2 = dx0 * dx0 + dx1 * dx1 + dx2 * dx2;
            float nrm = sqrtf(fmaxf(d2, 0.f) + 1e-5f);
            nrm_s[tid] = nrm;
            en_s[tid] = __expf(-nrm);
            norm_g[(size_t)bi * NN + j] = nrm;
        }
    }
    __syncthreads();

    // ---- phase 1: hk = h_cat @ W_in + b_in (K=128 -> 50 outs), then rbf*hk
    {
        int chc[4]; bool chv[4];
#pragma unroll
        for (int r = 0; r < 4; r++) { int ch = c4 + r; chv[r] = (ch < KK); chc[r] = chv[r] ? ch : (KK - 1); }
        float a0[4], a1[4];
#pragma unroll
        for (int r = 0; r < 4; r++) { float bv = b_in[chc[r]]; a0[r] = bv; a1[r] = bv; }

        const float* wp = W_in;
        for (int k = 0; k < 64; k += 4) {          // h_j rows
            float4 u0 = *(const float4*)&hj[p0][k];
            float4 u1 = *(const float4*)&hj[p1][k];
            float uu0[4] = {u0.x, u0.y, u0.z, u0.w};
            float uu1[4] = {u1.x, u1.y, u1.z, u1.w};
#pragma unroll
            for (int kk = 0; kk < 4; kk++) {
#pragma unroll
                for (int r = 0; r < 4; r++) {
                    float w = wp[chc[r]];
                    a0[r] += uu0[kk] * w;
                    a1[r] += uu1[kk] * w;
                }
                wp += KK;
            }
        }
        for (int k = 0; k < 64; k += 4) {          // h_i rows (pair-uniform)
            float4 u = *(const float4*)&hi_s[k];
            float uu[4] = {u.x, u.y, u.z, u.w};
#pragma unroll
            for (int kk = 0; kk < 4; kk++) {
#pragma unroll
                for (int r = 0; r < 4; r++) {
                    float w = wp[chc[r]];
                    a0[r] += uu[kk] * w;
                    a1[r] += uu[kk] * w;
                }
                wp += KK;
            }
        }
        float en0 = en_s[p0], en1 = en_s[p1];
#pragma unroll
        for (int r = 0; r < 4; r++) {
            if (chv[r]) {
                float mn = means[chc[r]], bt = betas[chc[r]];
                float e0 = en0 - mn, e1 = en1 - mn;
                rbfhk[p0][c4 + r] = __expf(-bt * e0 * e0) * a0[r];
                rbfhk[p1][c4 + r] = __expf(-bt * e1 * e1) * a1[r];
            }
        }
    }
    __syncthreads();

    // ---- phase 2: [h_cat, rbf*hk, norm] @ W_o1 + b_o1, silu -> s1
    {
        float4 bv = *(const float4*)&b_o1[c4];
        float a0[4] = {bv.x, bv.y, bv.z, bv.w};
        float a1[4] = {bv.x, bv.y, bv.z, bv.w};
        for (int k = 0; k < 64; k += 4) {          // h_j
            float4 u0 = *(const float4*)&hj[p0][k];
            float4 u1 = *(const float4*)&hj[p1][k];
            float uu0[4] = {u0.x, u0.y, u0.z, u0.w};
            float uu1[4] = {u1.x, u1.y, u1.z, u1.w};
#pragma unroll
            for (int kk = 0; kk < 4; kk++) {
                float4 w = *(const float4*)&W_o1[(k + kk) * HH + c4];
                a0[0] += uu0[kk] * w.x; a0[1] += uu0[kk] * w.y; a0[2] += uu0[kk] * w.z; a0[3] += uu0[kk] * w.w;
                a1[0] += uu1[kk] * w.x; a1[1] += uu1[kk] * w.y; a1[2] += uu1[kk] * w.z; a1[3] += uu1[kk] * w.w;
            }
        }
        for (int k = 0; k < 64; k += 4) {          // h_i (pair-uniform)
            float4 u = *(const float4*)&hi_s[k];
            float uu[4] = {u.x, u.y, u.z, u.w};
#pragma unroll
            for (int kk = 0; kk < 4; kk++) {
                float4 w = *(const float4*)&W_o1[(64 + k + kk) * HH + c4];
                float a = uu[kk];
                a0[0] += a * w.x; a0[1] += a * w.y; a0[2] += a * w.z; a0[3] += a * w.w;
                a1[0] += a * w.x; a1[1] += a * w.y; a1[2] += a * w.z; a1[3] += a * w.w;
            }
        }
        for (int kk = 0; kk < 48; kk += 4) {       // rbf*hk rows 128..175
            float4 u0 = *(const float4*)&rbfhk[p0][kk];
            float4 u1 = *(const float4*)&rbfhk[p1][kk];
            float uu0[4] = {u0.x, u0.y, u0.z, u0.w};
            float uu1[4] = {u1.x, u1.y, u1.z, u1.w};
#pragma unroll
            for (int q = 0; q < 4; q++) {
                float4 w = *(const float4*)&W_o1[(128 + kk + q) * HH + c4];
                a0[0] += uu0[q] * w.x; a0[1] += uu0[q] * w.y; a0[2] += uu0[q] * w.z; a0[3] += uu0[q] * w.w;
                a1[0] += uu1[q] * w.x; a1[1] += uu1[q] * w.y; a1[2] += uu1[q] * w.z; a1[3] += uu1[q] * w.w;
            }
        }
        {                                           // rows 176,177
            float2 u0 = *(const float2*)&rbfhk[p0][48];
            float2 u1 = *(const float2*)&rbfhk[p1][48];
            float4 w0 = *(const float4*)&W_o1[176 * HH + c4];
            float4 w1 = *(const float4*)&W_o1[177 * HH + c4];
            a0[0] += u0.x * w0.x + u0.y * w1.x; a0[1] += u0.x * w0.y + u0.y * w1.y;
            a0[2] += u0.x * w0.z + u0.y * w1.z; a0[3] += u0.x * w0.w + u0.y * w1.w;
            a1[0] += u1.x * w0.x + u1.y * w1.x; a1[1] += u1.x * w0.y + u1.y * w1.y;
            a1[2] += u1.x * w0.z + u1.y * w1.z; a1[3] += u1.x * w0.w + u1.y * w1.w;
        }
        {                                           // norm row 178
            float n0 = nrm_s[p0], n1 = nrm_s[p1];
            float4 w = *(const float4*)&W_o1[178 * HH + c4];
            a0[0] += n0 * w.x; a0[1] += n0 * w.y; a0[2] += n0 * w.z; a0[3] += n0 * w.w;
            a1[0] += n1 * w.x; a1[1] += n1 * w.y; a1[2] += n1 * w.z; a1[3] += n1 * w.w;
        }
        *(float4*)&s1[p0][c4] = make_float4(siluf(a0[0]), siluf(a0[1]), siluf(a0[2]), siluf(a0[3]));
        *(float4*)&s1[p1][c4] = make_float4(siluf(a1[0]), siluf(a1[1]), siluf(a1[2]), siluf(a1[3]));
    }
    __syncthreads();

    // ---- phase 3: s1 @ W_o2 + b_o2 -> he (store global + LDS alias of hj)
    {
        float4 bv = *(const float4*)&b_o2[c4];
        float a0[4] = {bv.x, bv.y, bv.z, bv.w};
        float a1[4] = {bv.x, bv.y, bv.z, bv.w};
        for (int k = 0; k < 64; k += 4) {
            float4 u0 = *(const float4*)&s1[p0][k];
            float4 u1 = *(const float4*)&s1[p1][k];
            float uu0[4] = {u0.x, u0.y, u0.z, u0.w};
            float uu1[4] = {u1.x, u1.y, u1.z, u1.w};
#pragma unroll
            for (int kk = 0; kk < 4; kk++) {
                float4 w = *(const float4*)&W_o2[(k + kk) * HH + c4];
                a0[0] += uu0[kk] * w.x; a0[1] += uu0[kk] * w.y; a0[2] += uu0[kk] * w.z; a0[3] += uu0[kk] * w.w;
                a1[0] += uu1[kk] * w.x; a1[1] += uu1[kk] * w.y; a1[2] += uu1[kk] * w.z; a1[3] += uu1[kk] * w.w;
            }
        }
        float4 he0 = make_float4(a0[0], a0[1], a0[2], a0[3]);
        float4 he1 = make_float4(a1[0], a1[1], a1[2], a1[3]);
        *(float4*)&hj[p0][c4] = he0;   // hj reads are done; reuse as he storage
        *(float4*)&hj[p1][c4] = he1;
        float4* out0 = (float4*)&he_mtx[((size_t)bi * NN + jt + p0) * HH + c4];
        float4* out1 = (float4*)&he_mtx[((size_t)bi * NN + jt + p1) * HH + c4];
        *out0 = he0;
        *out1 = he1;
    }
    __syncthreads();

    // ---- phase 4: sem logits = celu(he @ Ws + bs, alpha=2) - 1e5*eye
    if (tid < 128) {
        int p = tid >> 2, hd = tid & 3;
        float acc = bs[hd];
        for (int k = 0; k < 64; k += 4) {
            float4 u = *(const float4*)&hj[p][k];
            acc += u.x * Ws[k * 4 + hd] + u.y * Ws[(k + 1) * 4 + hd]
                 + u.z * Ws[(k + 2) * 4 + hd] + u.w * Ws[(k + 3) * 4 + hd];
        }
        float cel = acc > 0.f ? acc : 2.f * expm1f(0.5f * acc);
        int j = jt + p;
        if (i == j) cel -= 1e5f;
        sem_logit[((size_t)bi * NN + j) * 4 + hd] = cel;
    }
}

// ---------------------------------------------------------------------------
// K2: the three softmaxes over j. One block per (b,i), thread = j.
// ---------------------------------------------------------------------------
__device__ __forceinline__ float4 block_max4(float4 v, float4* buf) {
    int tid = threadIdx.x;
    buf[tid] = v;
    __syncthreads();
    for (int s = 128; s > 0; s >>= 1) {
        if (tid < s) {
            float4 o = buf[tid + s], m = buf[tid];
            m.x = fmaxf(m.x, o.x); m.y = fmaxf(m.y, o.y);
            m.z = fmaxf(m.z, o.z); m.w = fmaxf(m.w, o.w);
            buf[tid] = m;
        }
        __syncthreads();
    }
    float4 r = buf[0];
    __syncthreads();
    return r;
}

__device__ __forceinline__ float4 block_sum4(float4 v, float4* buf) {
    int tid = threadIdx.x;
    buf[tid] = v;
    __syncthreads();
    for (int s = 128; s > 0; s >>= 1) {
        if (tid < s) {
            float4 o = buf[tid + s], m = buf[tid];
            m.x += o.x; m.y += o.y; m.z += o.z; m.w += o.w;
            buf[tid] = m;
        }
        __syncthreads();
    }
    float4 r = buf[0];
    __syncthreads();
    return r;
}

__global__ __launch_bounds__(256) void k2_attn(
    const float* __restrict__ norm_g, const float* __restrict__ sem_logit,
    const float* __restrict__ log_gamma, float* __restrict__ comb_att)
{
    __shared__ float4 buf[256];
    const int bi = blockIdx.x;        // b*N + i
    const int i = bi & 255;
    const int j = threadIdx.x;
    const size_t base = (size_t)bi * NN + j;

    float g0 = __expf(log_gamma[0]);
    float g1 = __expf(log_gamma[1]);
    float g2 = __expf(log_gamma[2]);
    float g3 = __expf(log_gamma[3]);

    float nrm = norm_g[base];
    float pen = (j == i) ? 1e5f : 0.f;
    float nl = -(nrm + pen);
    float4 el = make_float4(nl * g0, nl * g1, nl * g2, nl * g3);
    float4 sl = ((const float4*)sem_logit)[base];

    float4 m = block_max4(el, buf);
    float4 ev = make_float4(__expf(el.x - m.x), __expf(el.y - m.y),
                            __expf(el.z - m.z), __expf(el.w - m.w));
    float4 sum = block_sum4(ev, buf);
    float4 eucl = make_float4(ev.x / sum.x, ev.y / sum.y, ev.z / sum.z, ev.w / sum.w);

    m = block_max4(sl, buf);
    float4 sv = make_float4(__expf(sl.x - m.x), __expf(sl.y - m.y),
                            __expf(sl.z - m.z), __expf(sl.w - m.w));
    sum = block_sum4(sv, buf);
    float4 sem = make_float4(sv.x / sum.x, sv.y / sum.y, sv.z / sum.z, sv.w / sum.w);

    float4 cl = make_float4(eucl.x * sem.x, eucl.y * sem.y, eucl.z * sem.z, eucl.w * sem.w);
    m = block_max4(cl, buf);
    float4 cv = make_float4(__expf(cl.x - m.x), __expf(cl.y - m.y),
                            __expf(cl.z - m.z), __expf(cl.w - m.w));
    sum = block_sum4(cv, buf);
    float4 ca = make_float4(cv.x / sum.x, cv.y / sum.y, cv.z / sum.z, cv.w / sum.w);

    ((float4*)comb_att)[base] = ca;
}

// ---------------------------------------------------------------------------
// K3: h_e_att build + coeff = tanh(h_e_att @ Wx) + reductions over j.
// ds_read_b128 inner loop (hea rows padded to 260 floats: conflict-free).
// h_e accumulated at staging time (thread owns column tid).
// ---------------------------------------------------------------------------
__global__ __launch_bounds__(256) void k3_spatial(
    const float* __restrict__ he_mtx, const float* __restrict__ comb_att,
    const float* __restrict__ x, const float* __restrict__ norm_g,
    const float* __restrict__ Wx, const float* __restrict__ Wv_mix,
    float* __restrict__ h_e, float* __restrict__ comb_norm,
    float* __restrict__ delta_v)
{
    __shared__ float hea[32][260];      // 33.3 KB, padded rows (1040B = 65*16)
    __shared__ float xd[32][4];
    __shared__ float red_cs[4][CC][3];  // 12 KB
    __shared__ float red_dv[256][3];    // 3 KB

    const int tid = threadIdx.x;
    const int g = tid >> 6;             // wave id -> j subgroup
    const int cc = tid & 63;
    const int cb = cc * 4;              // first owned Wx column
    const int bi = blockIdx.x;
    const int b = bi >> 8;
    const int i = bi & 255;

    const float4* Wx4 = (const float4*)Wx;
    const float wv0 = Wv_mix[cb + 0], wv1 = Wv_mix[cb + 1];
    const float wv2 = Wv_mix[cb + 2], wv3 = Wv_mix[cb + 3];

    float he_acc = 0.f;                 // column `tid` of h_e, fully owned
    float cs[4][3] = {{0.f,0.f,0.f},{0.f,0.f,0.f},{0.f,0.f,0.f},{0.f,0.f,0.f}};
    float dv0 = 0.f, dv1 = 0.f, dv2 = 0.f;

    const float* xb = x + (size_t)b * NN * 3;
    const float xi0 = xb[i * 3 + 0], xi1 = xb[i * 3 + 1], xi2 = xb[i * 3 + 2];

    const int jb = g * 8;

    for (int jt = 0; jt < NN; jt += 32) {
        for (int jj = 0; jj < 32; jj++) {
            int j = jt + jj;
            float hv = he_mtx[((size_t)bi * NN + j) * HH + (tid >> 2)];
            float av = comb_att[((size_t)bi * NN + j) * 4 + (tid & 3)];
            float val = hv * av;
            hea[jj][tid] = val;
            he_acc += val;
        }
        if (tid < 32) {
            int j = jt + tid;
            float nrm = norm_g[(size_t)bi * NN + j];
            float inv = 1.f / (nrm + 1e-5f);
            xd[tid][0] = (xb[j * 3 + 0] - xi0) * inv;
            xd[tid][1] = (xb[j * 3 + 1] - xi1) * inv;
            xd[tid][2] = (xb[j * 3 + 2] - xi2) * inv;
        }
        __syncthreads();

        float acc[8][4];
#pragma unroll
        for (int jj = 0; jj < 8; jj++)
            for (int r = 0; r < 4; r++) acc[jj][r] = 0.f;

        for (int k = 0; k < CC; k += 4) {
            float4 w0 = Wx4[(k + 0) * 64 + cc];
            float4 w1 = Wx4[(k + 1) * 64 + cc];
            float4 w2 = Wx4[(k + 2) * 64 + cc];
            float4 w3 = Wx4[(k + 3) * 64 + cc];
#pragma unroll
            for (int jj = 0; jj < 8; jj++) {
                float4 a = *(const float4*)&hea[jb + jj][k];
                acc[jj][0] += a.x * w0.x + a.y * w1.x + a.z * w2.x + a.w * w3.x;
                acc[jj][1] += a.x * w0.y + a.y * w1.y + a.z * w2.y + a.w * w3.y;
                acc[jj][2] += a.x * w0.z + a.y * w1.z + a.z * w2.z + a.w * w3.z;
                acc[jj][3] += a.x * w0.w + a.y * w1.w + a.z * w2.w + a.w * w3.w;
            }
        }

#pragma unroll
        for (int jj = 0; jj < 8; jj++) {
            int jl = jb + jj;
            float c0 = tanh_fast(acc[jj][0]);
            float c1 = tanh_fast(acc[jj][1]);
            float c2 = tanh_fast(acc[jj][2]);
            float c3 = tanh_fast(acc[jj][3]);
            float x0 = xd[jl][0], x1 = xd[jl][1], x2 = xd[jl][2];
            float wsum = c0 * wv0 + c1 * wv1 + c2 * wv2 + c3 * wv3;
            dv0 += x0 * wsum; dv1 += x1 * wsum; dv2 += x2 * wsum;
            cs[0][0] += x0 * c0; cs[0][1] += x1 * c0; cs[0][2] += x2 * c0;
            cs[1][0] += x0 * c1; cs[1][1] += x1 * c1; cs[1][2] += x2 * c1;
            cs[2][0] += x0 * c2; cs[2][1] += x1 * c2; cs[2][2] += x2 * c2;
            cs[3][0] += x0 * c3; cs[3][1] += x1 * c3; cs[3][2] += x2 * c3;
        }
        __syncthreads();   // before next tile overwrites hea
    }

    // h_e: column `tid` fully owned by this thread
    h_e[(size_t)bi * CC + tid] = he_acc;

    // cross-wave reductions for comb_norm / delta_v
#pragma unroll
    for (int r = 0; r < 4; r++)
        for (int t = 0; t < 3; t++) red_cs[g][cb + r][t] = cs[r][t];
    red_dv[tid][0] = dv0; red_dv[tid][1] = dv1; red_dv[tid][2] = dv2;
    __syncthreads();

    {
        int c = tid;
        float m0 = 0.f, m1 = 0.f, m2 = 0.f;
#pragma unroll
        for (int gg = 0; gg < 4; gg++) {
            m0 += red_cs[gg][c][0]; m1 += red_cs[gg][c][1]; m2 += red_cs[gg][c][2];
        }
        const float invn = 1.f / (float)NN;
        m0 *= invn; m1 *= invn; m2 *= invn;
        comb_norm[(size_t)bi * CC + c] = m0 * m0 + m1 * m1 + m2 * m2;
    }
    if (tid < 3) {
        float ssum = 0.f;
        for (int t = 0; t < 256; t++) ssum += red_dv[t][tid];
        delta_v[(size_t)bi * 3 + tid] = ssum * (1.f / (float)NN);
    }
}

// ---------------------------------------------------------------------------
// K4: node MLPs + velocity/position update. One block (64 thr) per (b,i).
// ---------------------------------------------------------------------------
__global__ __launch_bounds__(64) void k4_node(
    const float* __restrict__ h, const float* __restrict__ x, const float* __restrict__ v,
    const float* __restrict__ h_e, const float* __restrict__ comb_norm,
    const float* __restrict__ delta_v,
    const float* __restrict__ Wp1, const float* __restrict__ bp1,
    const float* __restrict__ Wp2, const float* __restrict__ bp2,
    const float* __restrict__ Wn1, const float* __restrict__ bn1,
    const float* __restrict__ Wn2, const float* __restrict__ bn2,
    const float* __restrict__ Wvel1, const float* __restrict__ bvel1,
    const float* __restrict__ Wvel2,
    float* __restrict__ out)
{
    __shared__ float cn[CC];
    __shared__ float inb[FF + CC + HH];   // [h, h_e, h_comb]
    __shared__ float tmp[HH];
    __shared__ float hn[HH];

    const int bi = blockIdx.x;
    const int t = threadIdx.x;

#pragma unroll
    for (int r = 0; r < 4; r++) {
        cn[r * 64 + t] = comb_norm[(size_t)bi * CC + r * 64 + t];
        inb[FF + r * 64 + t] = h_e[(size_t)bi * CC + r * 64 + t];
    }
    inb[t] = h[(size_t)bi * FF + t];
    __syncthreads();

    float acc = bp1[t];
#pragma unroll 8
    for (int k = 0; k < CC; k++) acc += cn[k] * Wp1[k * HH + t];
    tmp[t] = siluf(acc);
    __syncthreads();
    acc = bp2[t];
#pragma unroll 8
    for (int k = 0; k < HH; k++) acc += tmp[k] * Wp2[k * HH + t];
    inb[FF + CC + t] = siluf(acc);
    __syncthreads();

    acc = bn1[t];
#pragma unroll 8
    for (int k = 0; k < FF + CC + HH; k++) acc += inb[k] * Wn1[k * HH + t];
    float n1v = siluf(acc);
    __syncthreads();
    tmp[t] = n1v;
    __syncthreads();
    acc = bn2[t];
#pragma unroll 8
    for (int k = 0; k < HH; k++) acc += tmp[k] * Wn2[k * FF + t];
    float hnew = inb[t] + siluf(acc);
    hn[t] = hnew;
    out[(size_t)bi * FF + t] = hnew;
    __syncthreads();

    acc = bvel1[t];
#pragma unroll 8
    for (int k = 0; k < HH; k++) acc += hn[k] * Wvel1[k * HH + t];
    float val = siluf(acc) * Wvel2[t];
#pragma unroll
    for (int off = 32; off >= 1; off >>= 1) val += __shfl_xor(val, off, 64);
    float vscale = 2.f * sigmoidf_(val);

    if (t < 3) {
        float vv = v[(size_t)bi * 3 + t];
        float vn = delta_v[(size_t)bi * 3 + t] + vscale * vv;
        out[32768 + (size_t)bi * 3 + t] = x[(size_t)bi * 3 + t] + vn;  // x_new
        out[34304 + (size_t)bi * 3 + t] = vn;                           // v_new
    }
}

// ---------------------------------------------------------------------------
extern "C" void kernel_launch(void* const* d_in, const int* in_sizes, int n_in,
                              void* d_out, int out_size, void* d_ws, size_t ws_size,
                              hipStream_t stream)
{
    const float* h        = (const float*)d_in[0];
    const float* x        = (const float*)d_in[1];
    const float* v        = (const float*)d_in[2];
    const float* means    = (const float*)d_in[3];
    const float* betas    = (const float*)d_in[4];
    const float* W_in     = (const float*)d_in[5];
    const float* b_in     = (const float*)d_in[6];
    const float* W_o1     = (const float*)d_in[7];
    const float* b_o1     = (const float*)d_in[8];
    const float* W_o2     = (const float*)d_in[9];
    const float* b_o2     = (const float*)d_in[10];
    const float* Ws       = (const float*)d_in[11];
    const float* bs       = (const float*)d_in[12];
    const float* log_gamma= (const float*)d_in[13];
    const float* Wx       = (const float*)d_in[14];
    const float* Wp1      = (const float*)d_in[15];
    const float* bp1      = (const float*)d_in[16];
    const float* Wp2      = (const float*)d_in[17];
    const float* bp2      = (const float*)d_in[18];
    const float* Wn1      = (const float*)d_in[19];
    const float* bn1      = (const float*)d_in[20];
    const float* Wn2      = (const float*)d_in[21];
    const float* bn2      = (const float*)d_in[22];
    const float* Wv_mix   = (const float*)d_in[23];
    const float* Wvel1    = (const float*)d_in[24];
    const float* bvel1    = (const float*)d_in[25];
    const float* Wvel2    = (const float*)d_in[26];

    float* ws = (float*)d_ws;
    float* norm_g    = ws;                 // 131072
    float* he_mtx    = ws + 131072;        // 8388608
    float* sem_logit = ws + 8519680;       // 524288
    float* comb_att  = ws + 9043968;       // 524288
    float* h_e       = ws + 9568256;       // 131072
    float* comb_norm = ws + 9699328;       // 131072
    float* delta_v   = ws + 9830400;       // 1536

    k1_edge<<<dim3(NPAIR / 32), dim3(256), 0, stream>>>(
        h, x, means, betas, W_in, b_in, W_o1, b_o1, W_o2, b_o2, Ws, bs,
        he_mtx, sem_logit, norm_g);

    k2_attn<<<dim3(BN), dim3(256), 0, stream>>>(norm_g, sem_logit, log_gamma, comb_att);

    k3_spatial<<<dim3(BN), dim3(256), 0, stream>>>(
        he_mtx, comb_att, x, norm_g, Wx, Wv_mix, h_e, comb_norm, delta_v);

    k4_node<<<dim3(BN), dim3(64), 0, stream>>>(
        h, x, v, h_e, comb_norm, delta_v,
        Wp1, bp1, Wp2, bp2, Wn1, bn1, Wn2, bn2, Wvel1, bvel1, Wvel2,
        (float*)d_out);
}

// Round 3
// 572.662 us; speedup vs baseline: 1.7700x; 1.7700x over previous
//
#include <hip/hip_runtime.h>
#include <math.h>

#define NB 2
#define NN 256
#define FF 64
#define HH 64
#define NHEADS 4
#define KK 50
#define CC 256

constexpr int BN = NB * NN;          // 512
constexpr int NPAIR = NB * NN * NN;  // 131072

__device__ __forceinline__ float siluf(float v) { return v / (1.f + __expf(-v)); }
__device__ __forceinline__ float sigmoidf_(float v) { return 1.f / (1.f + __expf(-v)); }
__device__ __forceinline__ float tanh_fast(float x) {
    x = fminf(fmaxf(x, -15.f), 15.f);
    float e = __expf(2.f * x);
    return (e - 1.f) / (e + 1.f);
}

// ---------------------------------------------------------------------------
// K0: per-node precompute.
//   U[n] = h_n @ W_in[0:64]   + b_in   (50)
//   V[n] = h_n @ W_in[64:128]          (50)
//   P[n] = h_n @ W_o1[0:64]   + b_o1   (64)
//   Q[n] = h_n @ W_o1[64:128]          (64)
// One block (64 thr) per node; ~7.5 MMAC total.
// ---------------------------------------------------------------------------
__global__ __launch_bounds__(64) void k0_node_pre(
    const float* __restrict__ h,
    const float* __restrict__ W_in, const float* __restrict__ b_in,
    const float* __restrict__ W_o1, const float* __restrict__ b_o1,
    float* __restrict__ U, float* __restrict__ V,
    float* __restrict__ P, float* __restrict__ Q)
{
    __shared__ float hh[64];
    const int bn = blockIdx.x;
    const int t = threadIdx.x;
    hh[t] = h[(size_t)bn * FF + t];
    __syncthreads();

    float accP = b_o1[t], accQ = 0.f;
#pragma unroll 8
    for (int k = 0; k < 64; k++) {
        float hv = hh[k];
        accP += hv * W_o1[k * HH + t];
        accQ += hv * W_o1[(64 + k) * HH + t];
    }
    P[(size_t)bn * 64 + t] = accP;
    Q[(size_t)bn * 64 + t] = accQ;

    if (t < KK) {
        float aU = b_in[t], aV = 0.f;
#pragma unroll 8
        for (int k = 0; k < 64; k++) {
            float hv = hh[k];
            aU += hv * W_in[k * KK + t];
            aV += hv * W_in[(64 + k) * KK + t];
        }
        U[(size_t)bn * 64 + t] = aU;
        V[(size_t)bn * 64 + t] = aV;
    }
}

// ---------------------------------------------------------------------------
// K1: edge model, decomposed. One wave per pair; 4 pairs per 256-block.
//   layer1 = P[j] + Q[i] + (rbf*hk) @ W_o1[128:178] + norm*W_o1[178]
// Weight loads are fully coalesced 256B rows (L1-resident).
// ---------------------------------------------------------------------------
__global__ __launch_bounds__(256) void k1_edge(
    const float* __restrict__ x,
    const float* __restrict__ means, const float* __restrict__ betas,
    const float* __restrict__ U, const float* __restrict__ V,
    const float* __restrict__ P, const float* __restrict__ Q,
    const float* __restrict__ W_o1,
    const float* __restrict__ W_o2, const float* __restrict__ b_o2,
    const float* __restrict__ Ws, const float* __restrict__ bs,
    float* __restrict__ he_mtx, float* __restrict__ sem_logit,
    float* __restrict__ norm_g)
{
    __shared__ float rh[4][52];   // rbf*hk per pair (50 used; 208B rows, 16B aligned)
    __shared__ float s1[4][64];
    __shared__ float he[4][64];

    const int tid = threadIdx.x;
    const int s = tid >> 6;
    const int l = tid & 63;
    const int p = blockIdx.x * 4 + s;      // pair id = (b*N+i)*N + j
    const int b = p >> 16;
    const int rem = p & 65535;
    const int i = rem >> 8;
    const int j = rem & 255;
    const int bnj = b * NN + j;
    const int bni = b * NN + i;

    const float* xb = x + (size_t)b * NN * 3;
    float dx0 = xb[j * 3 + 0] - xb[i * 3 + 0];
    float dx1 = xb[j * 3 + 1] - xb[i * 3 + 1];
    float dx2 = xb[j * 3 + 2] - xb[i * 3 + 2];
    float d2 = dx0 * dx0 + dx1 * dx1 + dx2 * dx2;
    float nrm = sqrtf(fmaxf(d2, 0.f) + 1e-5f);

    if (l < KK) {
        float hk = U[(size_t)bnj * 64 + l] + V[(size_t)bni * 64 + l];
        float e = __expf(-nrm) - means[l];
        rh[s][l] = __expf(-betas[l] * e * e) * hk;
    }
    __syncthreads();

    // layer 1: P[j] + Q[i] + rh @ W_o1[128:178] + nrm * W_o1[178]
    {
        float acc = P[(size_t)bnj * 64 + l] + Q[(size_t)bni * 64 + l]
                  + nrm * W_o1[178 * HH + l];
#pragma unroll
        for (int k = 0; k < 48; k += 4) {
            float4 u = *(const float4*)&rh[s][k];
            acc += u.x * W_o1[(128 + k) * HH + l];
            acc += u.y * W_o1[(129 + k) * HH + l];
            acc += u.z * W_o1[(130 + k) * HH + l];
            acc += u.w * W_o1[(131 + k) * HH + l];
        }
        {
            float2 u = *(const float2*)&rh[s][48];
            acc += u.x * W_o1[176 * HH + l] + u.y * W_o1[177 * HH + l];
        }
        s1[s][l] = siluf(acc);
    }
    __syncthreads();

    // layer 2: s1 @ W_o2 + b_o2 -> he
    {
        float acc = b_o2[l];
#pragma unroll
        for (int k = 0; k < 64; k += 4) {
            float4 u = *(const float4*)&s1[s][k];
            acc += u.x * W_o2[(k + 0) * HH + l];
            acc += u.y * W_o2[(k + 1) * HH + l];
            acc += u.z * W_o2[(k + 2) * HH + l];
            acc += u.w * W_o2[(k + 3) * HH + l];
        }
        he[s][l] = acc;
        he_mtx[(size_t)p * HH + l] = acc;
    }
    __syncthreads();

    // semantic attention logits
    if (l < NHEADS) {
        float acc = bs[l];
#pragma unroll
        for (int k = 0; k < 64; k += 4) {
            float4 u = *(const float4*)&he[s][k];
            acc += u.x * Ws[(k + 0) * 4 + l] + u.y * Ws[(k + 1) * 4 + l]
                 + u.z * Ws[(k + 2) * 4 + l] + u.w * Ws[(k + 3) * 4 + l];
        }
        float cel = acc > 0.f ? acc : 2.f * expm1f(0.5f * acc);
        if (i == j) cel -= 1e5f;
        sem_logit[(size_t)p * 4 + l] = cel;
    }
    if (l == 0) norm_g[p] = nrm;
}

// ---------------------------------------------------------------------------
// K2: the three softmaxes over j. One block per (b,i), thread = j.
// ---------------------------------------------------------------------------
__device__ __forceinline__ float4 block_max4(float4 v, float4* buf) {
    int tid = threadIdx.x;
    buf[tid] = v;
    __syncthreads();
    for (int s = 128; s > 0; s >>= 1) {
        if (tid < s) {
            float4 o = buf[tid + s], m = buf[tid];
            m.x = fmaxf(m.x, o.x); m.y = fmaxf(m.y, o.y);
            m.z = fmaxf(m.z, o.z); m.w = fmaxf(m.w, o.w);
            buf[tid] = m;
        }
        __syncthreads();
    }
    float4 r = buf[0];
    __syncthreads();
    return r;
}

__device__ __forceinline__ float4 block_sum4(float4 v, float4* buf) {
    int tid = threadIdx.x;
    buf[tid] = v;
    __syncthreads();
    for (int s = 128; s > 0; s >>= 1) {
        if (tid < s) {
            float4 o = buf[tid + s], m = buf[tid];
            m.x += o.x; m.y += o.y; m.z += o.z; m.w += o.w;
            buf[tid] = m;
        }
        __syncthreads();
    }
    float4 r = buf[0];
    __syncthreads();
    return r;
}

__global__ __launch_bounds__(256) void k2_attn(
    const float* __restrict__ norm_g, const float* __restrict__ sem_logit,
    const float* __restrict__ log_gamma, float* __restrict__ comb_att)
{
    __shared__ float4 buf[256];
    const int bi = blockIdx.x;        // b*N + i
    const int i = bi & 255;
    const int j = threadIdx.x;
    const size_t base = (size_t)bi * NN + j;

    float g0 = __expf(log_gamma[0]);
    float g1 = __expf(log_gamma[1]);
    float g2 = __expf(log_gamma[2]);
    float g3 = __expf(log_gamma[3]);

    float nrm = norm_g[base];
    float pen = (j == i) ? 1e5f : 0.f;
    float nl = -(nrm + pen);
    float4 el = make_float4(nl * g0, nl * g1, nl * g2, nl * g3);
    float4 sl = ((const float4*)sem_logit)[base];

    float4 m = block_max4(el, buf);
    float4 ev = make_float4(__expf(el.x - m.x), __expf(el.y - m.y),
                            __expf(el.z - m.z), __expf(el.w - m.w));
    float4 sum = block_sum4(ev, buf);
    float4 eucl = make_float4(ev.x / sum.x, ev.y / sum.y, ev.z / sum.z, ev.w / sum.w);

    m = block_max4(sl, buf);
    float4 sv = make_float4(__expf(sl.x - m.x), __expf(sl.y - m.y),
                            __expf(sl.z - m.z), __expf(sl.w - m.w));
    sum = block_sum4(sv, buf);
    float4 sem = make_float4(sv.x / sum.x, sv.y / sum.y, sv.z / sum.z, sv.w / sum.w);

    float4 cl = make_float4(eucl.x * sem.x, eucl.y * sem.y, eucl.z * sem.z, eucl.w * sem.w);
    m = block_max4(cl, buf);
    float4 cv = make_float4(__expf(cl.x - m.x), __expf(cl.y - m.y),
                            __expf(cl.z - m.z), __expf(cl.w - m.w));
    sum = block_sum4(cv, buf);
    float4 ca = make_float4(cv.x / sum.x, cv.y / sum.y, cv.z / sum.z, cv.w / sum.w);

    ((float4*)comb_att)[base] = ca;
}

// ---------------------------------------------------------------------------
// K3: h_e_att build + coeff = tanh(h_e_att @ Wx) + reductions over j.
// (round-1 verified version)
// ---------------------------------------------------------------------------
__global__ __launch_bounds__(256) void k3_spatial(
    const float* __restrict__ he_mtx, const float* __restrict__ comb_att,
    const float* __restrict__ x, const float* __restrict__ norm_g,
    const float* __restrict__ Wx, const float* __restrict__ Wv_mix,
    float* __restrict__ h_e, float* __restrict__ comb_norm,
    float* __restrict__ delta_v)
{
    __shared__ float hea[32][CC];       // 32 KB: h_e_att tile [j][c]
    __shared__ float xd[32][4];
    __shared__ float red_he[4][CC];
    __shared__ float red_cs[4][CC][3];
    __shared__ float red_dv[256][3];

    const int tid = threadIdx.x;
    const int g = tid >> 6;             // wave id -> j subgroup
    const int cc = tid & 63;
    const int cb = cc * 4;              // first owned Wx column
    const int bi = blockIdx.x;
    const int b = bi >> 8;
    const int i = bi & 255;

    const float4* Wx4 = (const float4*)Wx;
    const float wv0 = Wv_mix[cb + 0], wv1 = Wv_mix[cb + 1];
    const float wv2 = Wv_mix[cb + 2], wv3 = Wv_mix[cb + 3];

    float he_s0 = 0.f, he_s1 = 0.f, he_s2 = 0.f, he_s3 = 0.f;
    float cs[4][3] = {{0.f,0.f,0.f},{0.f,0.f,0.f},{0.f,0.f,0.f},{0.f,0.f,0.f}};
    float dv0 = 0.f, dv1 = 0.f, dv2 = 0.f;

    const float* xb = x + (size_t)b * NN * 3;
    const float xi0 = xb[i * 3 + 0], xi1 = xb[i * 3 + 1], xi2 = xb[i * 3 + 2];

    for (int jt = 0; jt < NN; jt += 32) {
        for (int jj = 0; jj < 32; jj++) {
            int j = jt + jj;
            float hv = he_mtx[((size_t)bi * NN + j) * HH + (tid >> 2)];
            float av = comb_att[((size_t)bi * NN + j) * 4 + (tid & 3)];
            hea[jj][tid] = hv * av;
        }
        if (tid < 32) {
            int j = jt + tid;
            float nrm = norm_g[(size_t)bi * NN + j];
            float inv = 1.f / (nrm + 1e-5f);
            xd[tid][0] = (xb[j * 3 + 0] - xi0) * inv;
            xd[tid][1] = (xb[j * 3 + 1] - xi1) * inv;
            xd[tid][2] = (xb[j * 3 + 2] - xi2) * inv;
        }
        __syncthreads();

        float acc[8][4];
#pragma unroll
        for (int jj = 0; jj < 8; jj++)
            for (int r = 0; r < 4; r++) acc[jj][r] = 0.f;

        const int jb = g * 8;
#pragma unroll 4
        for (int k = 0; k < CC; k++) {
            float4 w = Wx4[k * 64 + cc];
#pragma unroll
            for (int jj = 0; jj < 8; jj++) {
                float a = hea[jb + jj][k];
                acc[jj][0] += a * w.x; acc[jj][1] += a * w.y;
                acc[jj][2] += a * w.z; acc[jj][3] += a * w.w;
            }
        }

#pragma unroll
        for (int jj = 0; jj < 8; jj++) {
            int jl = jb + jj;
            float c0 = tanh_fast(acc[jj][0]);
            float c1 = tanh_fast(acc[jj][1]);
            float c2 = tanh_fast(acc[jj][2]);
            float c3 = tanh_fast(acc[jj][3]);
            he_s0 += hea[jl][cb + 0]; he_s1 += hea[jl][cb + 1];
            he_s2 += hea[jl][cb + 2]; he_s3 += hea[jl][cb + 3];
            float x0 = xd[jl][0], x1 = xd[jl][1], x2 = xd[jl][2];
            float wsum = c0 * wv0 + c1 * wv1 + c2 * wv2 + c3 * wv3;
            dv0 += x0 * wsum; dv1 += x1 * wsum; dv2 += x2 * wsum;
            cs[0][0] += x0 * c0; cs[0][1] += x1 * c0; cs[0][2] += x2 * c0;
            cs[1][0] += x0 * c1; cs[1][1] += x1 * c1; cs[1][2] += x2 * c1;
            cs[2][0] += x0 * c2; cs[2][1] += x1 * c2; cs[2][2] += x2 * c2;
            cs[3][0] += x0 * c3; cs[3][1] += x1 * c3; cs[3][2] += x2 * c3;
        }
        __syncthreads();   // before next tile overwrites hea
    }

    // cross-wave reductions
    red_he[g][cb + 0] = he_s0; red_he[g][cb + 1] = he_s1;
    red_he[g][cb + 2] = he_s2; red_he[g][cb + 3] = he_s3;
#pragma unroll
    for (int r = 0; r < 4; r++)
        for (int t = 0; t < 3; t++) red_cs[g][cb + r][t] = cs[r][t];
    red_dv[tid][0] = dv0; red_dv[tid][1] = dv1; red_dv[tid][2] = dv2;
    __syncthreads();

    {
        int c = tid;
        float hv = red_he[0][c] + red_he[1][c] + red_he[2][c] + red_he[3][c];
        h_e[(size_t)bi * CC + c] = hv;
        float m0 = 0.f, m1 = 0.f, m2 = 0.f;
#pragma unroll
        for (int gg = 0; gg < 4; gg++) {
            m0 += red_cs[gg][c][0]; m1 += red_cs[gg][c][1]; m2 += red_cs[gg][c][2];
        }
        const float invn = 1.f / (float)NN;
        m0 *= invn; m1 *= invn; m2 *= invn;
        comb_norm[(size_t)bi * CC + c] = m0 * m0 + m1 * m1 + m2 * m2;
    }
    if (tid < 3) {
        float ssum = 0.f;
        for (int t = 0; t < 256; t++) ssum += red_dv[t][tid];
        delta_v[(size_t)bi * 3 + tid] = ssum * (1.f / (float)NN);
    }
}

// ---------------------------------------------------------------------------
// K4: node MLPs + velocity/position update. One block (64 thr) per (b,i).
// ---------------------------------------------------------------------------
__global__ __launch_bounds__(64) void k4_node(
    const float* __restrict__ h, const float* __restrict__ x, const float* __restrict__ v,
    const float* __restrict__ h_e, const float* __restrict__ comb_norm,
    const float* __restrict__ delta_v,
    const float* __restrict__ Wp1, const float* __restrict__ bp1,
    const float* __restrict__ Wp2, const float* __restrict__ bp2,
    const float* __restrict__ Wn1, const float* __restrict__ bn1,
    const float* __restrict__ Wn2, const float* __restrict__ bn2,
    const float* __restrict__ Wvel1, const float* __restrict__ bvel1,
    const float* __restrict__ Wvel2,
    float* __restrict__ out)
{
    __shared__ float cn[CC];
    __shared__ float inb[FF + CC + HH];   // [h, h_e, h_comb]
    __shared__ float tmp[HH];
    __shared__ float hn[HH];

    const int bi = blockIdx.x;
    const int t = threadIdx.x;

#pragma unroll
    for (int r = 0; r < 4; r++) {
        cn[r * 64 + t] = comb_norm[(size_t)bi * CC + r * 64 + t];
        inb[FF + r * 64 + t] = h_e[(size_t)bi * CC + r * 64 + t];
    }
    inb[t] = h[(size_t)bi * FF + t];
    __syncthreads();

    float acc = bp1[t];
#pragma unroll 8
    for (int k = 0; k < CC; k++) acc += cn[k] * Wp1[k * HH + t];
    tmp[t] = siluf(acc);
    __syncthreads();
    acc = bp2[t];
#pragma unroll 8
    for (int k = 0; k < HH; k++) acc += tmp[k] * Wp2[k * HH + t];
    inb[FF + CC + t] = siluf(acc);
    __syncthreads();

    acc = bn1[t];
#pragma unroll 8
    for (int k = 0; k < FF + CC + HH; k++) acc += inb[k] * Wn1[k * HH + t];
    float n1v = siluf(acc);
    __syncthreads();
    tmp[t] = n1v;
    __syncthreads();
    acc = bn2[t];
#pragma unroll 8
    for (int k = 0; k < HH; k++) acc += tmp[k] * Wn2[k * FF + t];
    float hnew = inb[t] + siluf(acc);
    hn[t] = hnew;
    out[(size_t)bi * FF + t] = hnew;
    __syncthreads();

    acc = bvel1[t];
#pragma unroll 8
    for (int k = 0; k < HH; k++) acc += hn[k] * Wvel1[k * HH + t];
    float val = siluf(acc) * Wvel2[t];
#pragma unroll
    for (int off = 32; off >= 1; off >>= 1) val += __shfl_xor(val, off, 64);
    float vscale = 2.f * sigmoidf_(val);

    if (t < 3) {
        float vv = v[(size_t)bi * 3 + t];
        float vn = delta_v[(size_t)bi * 3 + t] + vscale * vv;
        out[32768 + (size_t)bi * 3 + t] = x[(size_t)bi * 3 + t] + vn;  // x_new
        out[34304 + (size_t)bi * 3 + t] = vn;                           // v_new
    }
}

// ---------------------------------------------------------------------------
extern "C" void kernel_launch(void* const* d_in, const int* in_sizes, int n_in,
                              void* d_out, int out_size, void* d_ws, size_t ws_size,
                              hipStream_t stream)
{
    const float* h        = (const float*)d_in[0];
    const float* x        = (const float*)d_in[1];
    const float* v        = (const float*)d_in[2];
    const float* means    = (const float*)d_in[3];
    const float* betas    = (const float*)d_in[4];
    const float* W_in     = (const float*)d_in[5];
    const float* b_in     = (const float*)d_in[6];
    const float* W_o1     = (const float*)d_in[7];
    const float* b_o1     = (const float*)d_in[8];
    const float* W_o2     = (const float*)d_in[9];
    const float* b_o2     = (const float*)d_in[10];
    const float* Ws       = (const float*)d_in[11];
    const float* bs       = (const float*)d_in[12];
    const float* log_gamma= (const float*)d_in[13];
    const float* Wx       = (const float*)d_in[14];
    const float* Wp1      = (const float*)d_in[15];
    const float* bp1      = (const float*)d_in[16];
    const float* Wp2      = (const float*)d_in[17];
    const float* bp2      = (const float*)d_in[18];
    const float* Wn1      = (const float*)d_in[19];
    const float* bn1      = (const float*)d_in[20];
    const float* Wn2      = (const float*)d_in[21];
    const float* bn2      = (const float*)d_in[22];
    const float* Wv_mix   = (const float*)d_in[23];
    const float* Wvel1    = (const float*)d_in[24];
    const float* bvel1    = (const float*)d_in[25];
    const float* Wvel2    = (const float*)d_in[26];

    float* ws = (float*)d_ws;
    float* norm_g    = ws;                 // 131072
    float* he_mtx    = ws + 131072;        // 8388608
    float* sem_logit = ws + 8519680;       // 524288
    float* comb_att  = ws + 9043968;       // 524288 (UVPQ aliased here pre-k2)
    float* h_e       = ws + 9568256;       // 131072
    float* comb_norm = ws + 9699328;       // 131072
    float* delta_v   = ws + 9830400;       // 1536

    // U,V,P,Q live in the comb_att region: dead before k2 writes comb_att.
    float* U = comb_att;                   // 512*64
    float* V = comb_att + 32768;
    float* P = comb_att + 65536;
    float* Q = comb_att + 98304;

    k0_node_pre<<<dim3(BN), dim3(64), 0, stream>>>(
        h, W_in, b_in, W_o1, b_o1, U, V, P, Q);

    k1_edge<<<dim3(NPAIR / 4), dim3(256), 0, stream>>>(
        x, means, betas, U, V, P, Q, W_o1, W_o2, b_o2, Ws, bs,
        he_mtx, sem_logit, norm_g);

    k2_attn<<<dim3(BN), dim3(256), 0, stream>>>(norm_g, sem_logit, log_gamma, comb_att);

    k3_spatial<<<dim3(BN), dim3(256), 0, stream>>>(
        he_mtx, comb_att, x, norm_g, Wx, Wv_mix, h_e, comb_norm, delta_v);

    k4_node<<<dim3(BN), dim3(64), 0, stream>>>(
        h, x, v, h_e, comb_norm, delta_v,
        Wp1, bp1, Wp2, bp2, Wn1, bn1, Wn2, bn2, Wvel1, bvel1, Wvel2,
        (float*)d_out);
}

// Round 4
// 425.707 us; speedup vs baseline: 2.3810x; 1.3452x over previous
//
#include <hip/hip_runtime.h>
#include <math.h>

#define NB 2
#define NN 256
#define FF 64
#define HH 64
#define NHEADS 4
#define KK 50
#define CC 256

constexpr int BN = NB * NN;          // 512
constexpr int NPAIR = NB * NN * NN;  // 131072

typedef __attribute__((ext_vector_type(8))) short bf16x8;
typedef __attribute__((ext_vector_type(4))) float f32x4v;

__device__ __forceinline__ float siluf(float v) { return v / (1.f + __expf(-v)); }
__device__ __forceinline__ float sigmoidf_(float v) { return 1.f / (1.f + __expf(-v)); }
__device__ __forceinline__ float tanh_fast(float x) {
    x = fminf(fmaxf(x, -15.f), 15.f);
    float e = __expf(2.f * x);
    return (e - 1.f) / (e + 1.f);
}
__device__ __forceinline__ unsigned short f2bf(float f) {
    union { float f; unsigned u; } v; v.f = f;
    unsigned r = v.u + 0x7fffu + ((v.u >> 16) & 1u);
    return (unsigned short)(r >> 16);
}

// ---------------------------------------------------------------------------
// K0: per-node precompute (U,V from W_in halves; P,Q from W_o1 halves).
// ---------------------------------------------------------------------------
__global__ __launch_bounds__(64) void k0_node_pre(
    const float* __restrict__ h,
    const float* __restrict__ W_in, const float* __restrict__ b_in,
    const float* __restrict__ W_o1, const float* __restrict__ b_o1,
    float* __restrict__ U, float* __restrict__ V,
    float* __restrict__ P, float* __restrict__ Q)
{
    __shared__ float hh[64];
    const int bn = blockIdx.x;
    const int t = threadIdx.x;
    hh[t] = h[(size_t)bn * FF + t];
    __syncthreads();

    float accP = b_o1[t], accQ = 0.f;
#pragma unroll 8
    for (int k = 0; k < 64; k++) {
        float hv = hh[k];
        accP += hv * W_o1[k * HH + t];
        accQ += hv * W_o1[(64 + k) * HH + t];
    }
    P[(size_t)bn * 64 + t] = accP;
    Q[(size_t)bn * 64 + t] = accQ;

    if (t < KK) {
        float aU = b_in[t], aV = 0.f;
#pragma unroll 8
        for (int k = 0; k < 64; k++) {
            float hv = hh[k];
            aU += hv * W_in[k * KK + t];
            aV += hv * W_in[(64 + k) * KK + t];
        }
        U[(size_t)bn * 64 + t] = aU;
        V[(size_t)bn * 64 + t] = aV;
    }
}

// ---------------------------------------------------------------------------
// K0b: Wx [k][n] fp32 -> WxT [n][k] bf16 (B^T layout for MFMA B-fragments).
// Runs AFTER k2 (WxT lives in the dead sem_logit region).
// ---------------------------------------------------------------------------
__global__ __launch_bounds__(256) void k0b_wxt(
    const float* __restrict__ Wx, unsigned short* __restrict__ WxT)
{
    int idx = blockIdx.x * 256 + threadIdx.x;   // 65536 total
    int n = idx >> 8, k = idx & 255;
    WxT[idx] = f2bf(Wx[k * 256 + n]);
}

// ---------------------------------------------------------------------------
// K1: edge model, decomposed (round-3 verified).
// ---------------------------------------------------------------------------
__global__ __launch_bounds__(256) void k1_edge(
    const float* __restrict__ x,
    const float* __restrict__ means, const float* __restrict__ betas,
    const float* __restrict__ U, const float* __restrict__ V,
    const float* __restrict__ P, const float* __restrict__ Q,
    const float* __restrict__ W_o1,
    const float* __restrict__ W_o2, const float* __restrict__ b_o2,
    const float* __restrict__ Ws, const float* __restrict__ bs,
    float* __restrict__ he_mtx, float* __restrict__ sem_logit,
    float* __restrict__ norm_g)
{
    __shared__ float rh[4][52];
    __shared__ float s1[4][64];
    __shared__ float he[4][64];

    const int tid = threadIdx.x;
    const int s = tid >> 6;
    const int l = tid & 63;
    const int p = blockIdx.x * 4 + s;
    const int b = p >> 16;
    const int rem = p & 65535;
    const int i = rem >> 8;
    const int j = rem & 255;
    const int bnj = b * NN + j;
    const int bni = b * NN + i;

    const float* xb = x + (size_t)b * NN * 3;
    float dx0 = xb[j * 3 + 0] - xb[i * 3 + 0];
    float dx1 = xb[j * 3 + 1] - xb[i * 3 + 1];
    float dx2 = xb[j * 3 + 2] - xb[i * 3 + 2];
    float d2 = dx0 * dx0 + dx1 * dx1 + dx2 * dx2;
    float nrm = sqrtf(fmaxf(d2, 0.f) + 1e-5f);

    if (l < KK) {
        float hk = U[(size_t)bnj * 64 + l] + V[(size_t)bni * 64 + l];
        float e = __expf(-nrm) - means[l];
        rh[s][l] = __expf(-betas[l] * e * e) * hk;
    }
    __syncthreads();

    {
        float acc = P[(size_t)bnj * 64 + l] + Q[(size_t)bni * 64 + l]
                  + nrm * W_o1[178 * HH + l];
#pragma unroll
        for (int k = 0; k < 48; k += 4) {
            float4 u = *(const float4*)&rh[s][k];
            acc += u.x * W_o1[(128 + k) * HH + l];
            acc += u.y * W_o1[(129 + k) * HH + l];
            acc += u.z * W_o1[(130 + k) * HH + l];
            acc += u.w * W_o1[(131 + k) * HH + l];
        }
        {
            float2 u = *(const float2*)&rh[s][48];
            acc += u.x * W_o1[176 * HH + l] + u.y * W_o1[177 * HH + l];
        }
        s1[s][l] = siluf(acc);
    }
    __syncthreads();

    {
        float acc = b_o2[l];
#pragma unroll
        for (int k = 0; k < 64; k += 4) {
            float4 u = *(const float4*)&s1[s][k];
            acc += u.x * W_o2[(k + 0) * HH + l];
            acc += u.y * W_o2[(k + 1) * HH + l];
            acc += u.z * W_o2[(k + 2) * HH + l];
            acc += u.w * W_o2[(k + 3) * HH + l];
        }
        he[s][l] = acc;
        he_mtx[(size_t)p * HH + l] = acc;
    }
    __syncthreads();

    if (l < NHEADS) {
        float acc = bs[l];
#pragma unroll
        for (int k = 0; k < 64; k += 4) {
            float4 u = *(const float4*)&he[s][k];
            acc += u.x * Ws[(k + 0) * 4 + l] + u.y * Ws[(k + 1) * 4 + l]
                 + u.z * Ws[(k + 2) * 4 + l] + u.w * Ws[(k + 3) * 4 + l];
        }
        float cel = acc > 0.f ? acc : 2.f * expm1f(0.5f * acc);
        if (i == j) cel -= 1e5f;
        sem_logit[(size_t)p * 4 + l] = cel;
    }
    if (l == 0) norm_g[p] = nrm;
}

// ---------------------------------------------------------------------------
// K2: the three softmaxes over j (round-1 verified).
// ---------------------------------------------------------------------------
__device__ __forceinline__ float4 block_max4(float4 v, float4* buf) {
    int tid = threadIdx.x;
    buf[tid] = v;
    __syncthreads();
    for (int s = 128; s > 0; s >>= 1) {
        if (tid < s) {
            float4 o = buf[tid + s], m = buf[tid];
            m.x = fmaxf(m.x, o.x); m.y = fmaxf(m.y, o.y);
            m.z = fmaxf(m.z, o.z); m.w = fmaxf(m.w, o.w);
            buf[tid] = m;
        }
        __syncthreads();
    }
    float4 r = buf[0];
    __syncthreads();
    return r;
}

__device__ __forceinline__ float4 block_sum4(float4 v, float4* buf) {
    int tid = threadIdx.x;
    buf[tid] = v;
    __syncthreads();
    for (int s = 128; s > 0; s >>= 1) {
        if (tid < s) {
            float4 o = buf[tid + s], m = buf[tid];
            m.x += o.x; m.y += o.y; m.z += o.z; m.w += o.w;
            buf[tid] = m;
        }
        __syncthreads();
    }
    float4 r = buf[0];
    __syncthreads();
    return r;
}

__global__ __launch_bounds__(256) void k2_attn(
    const float* __restrict__ norm_g, const float* __restrict__ sem_logit,
    const float* __restrict__ log_gamma, float* __restrict__ comb_att)
{
    __shared__ float4 buf[256];
    const int bi = blockIdx.x;
    const int i = bi & 255;
    const int j = threadIdx.x;
    const size_t base = (size_t)bi * NN + j;

    float g0 = __expf(log_gamma[0]);
    float g1 = __expf(log_gamma[1]);
    float g2 = __expf(log_gamma[2]);
    float g3 = __expf(log_gamma[3]);

    float nrm = norm_g[base];
    float pen = (j == i) ? 1e5f : 0.f;
    float nl = -(nrm + pen);
    float4 el = make_float4(nl * g0, nl * g1, nl * g2, nl * g3);
    float4 sl = ((const float4*)sem_logit)[base];

    float4 m = block_max4(el, buf);
    float4 ev = make_float4(__expf(el.x - m.x), __expf(el.y - m.y),
                            __expf(el.z - m.z), __expf(el.w - m.w));
    float4 sum = block_sum4(ev, buf);
    float4 eucl = make_float4(ev.x / sum.x, ev.y / sum.y, ev.z / sum.z, ev.w / sum.w);

    m = block_max4(sl, buf);
    float4 sv = make_float4(__expf(sl.x - m.x), __expf(sl.y - m.y),
                            __expf(sl.z - m.z), __expf(sl.w - m.w));
    sum = block_sum4(sv, buf);
    float4 sem = make_float4(sv.x / sum.x, sv.y / sum.y, sv.z / sum.z, sv.w / sum.w);

    float4 cl = make_float4(eucl.x * sem.x, eucl.y * sem.y, eucl.z * sem.z, eucl.w * sem.w);
    m = block_max4(cl, buf);
    float4 cv = make_float4(__expf(cl.x - m.x), __expf(cl.y - m.y),
                            __expf(cl.z - m.z), __expf(cl.w - m.w));
    sum = block_sum4(cv, buf);
    float4 ca = make_float4(cv.x / sum.x, cv.y / sum.y, cv.z / sum.z, cv.w / sum.w);

    ((float4*)comb_att)[base] = ca;
}

// ---------------------------------------------------------------------------
// K3: bf16 MFMA version.
// Per (b,i) block: 4 passes of M=64 j-rows. hea staged bf16 in LDS
// [64][264] (row stride 264 -> uniform 8 words/bank for b128 frag reads).
// Wave w owns cols w*64..w*64+63 (4x4 grid of 16x16 tiles, acc 64 VGPR).
// A-frag: ds_read_b128; B-frag: 16B global from WxT bf16 (L2-hot).
// C layout: col=lane&15, row=(lane>>4)*4+reg (m89-verified).
// h_e accumulated at staging (thread owns column tid).
// ---------------------------------------------------------------------------
__global__ __launch_bounds__(256) void k3_spatial(
    const float* __restrict__ he_mtx, const float* __restrict__ comb_att,
    const float* __restrict__ x, const float* __restrict__ norm_g,
    const unsigned short* __restrict__ WxT, const float* __restrict__ Wv_mix,
    float* __restrict__ h_e, float* __restrict__ comb_norm,
    float* __restrict__ delta_v)
{
    __shared__ unsigned short hea[64 * 264];   // 33 KB
    __shared__ float4 xds[64];                 // 1 KB
    __shared__ float dvbuf[4][3];

    const int tid = threadIdx.x;
    const int l = tid & 63;
    const int w = tid >> 6;
    const int lrow = l >> 4;        // quad 0..3
    const int lcol = l & 15;
    const int wcol = w * 64;
    const int bi = blockIdx.x;
    const int b = bi >> 8;
    const int i = bi & 255;

    const float* xb = x + (size_t)b * NN * 3;
    const float xi0 = xb[i * 3 + 0], xi1 = xb[i * 3 + 1], xi2 = xb[i * 3 + 2];

    float wv_l[4];
#pragma unroll
    for (int nt = 0; nt < 4; nt++) wv_l[nt] = Wv_mix[wcol + nt * 16 + lcol];

    float cs[4][3] = {{0.f,0.f,0.f},{0.f,0.f,0.f},{0.f,0.f,0.f},{0.f,0.f,0.f}};
    float dv[3] = {0.f, 0.f, 0.f};
    float he_acc = 0.f;

    const int hh_idx = tid >> 2;    // he_mtx channel for this thread's column
    const int hd_idx = tid & 3;     // head index

    for (int pass = 0; pass < 4; pass++) {
        const int jt = pass * 64;

        // ---- stage hea tile (bf16) + accumulate h_e column
        for (int jj = 0; jj < 64; jj++) {
            int j = jt + jj;
            float hv = he_mtx[((size_t)bi * NN + j) * HH + hh_idx];
            float av = comb_att[((size_t)bi * NN + j) * 4 + hd_idx];
            float pval = hv * av;
            he_acc += pval;
            hea[jj * 264 + tid] = f2bf(pval);
        }
        if (tid < 64) {
            int j = jt + tid;
            float nrm = norm_g[(size_t)bi * NN + j];
            float inv = 1.f / (nrm + 1e-5f);
            xds[tid] = make_float4((xb[j * 3 + 0] - xi0) * inv,
                                   (xb[j * 3 + 1] - xi1) * inv,
                                   (xb[j * 3 + 2] - xi2) * inv, 0.f);
        }
        __syncthreads();

        // ---- MFMA: [64 j] x [256 k] @ WxT -> wave's 64 cols
        f32x4v acc[4][4];
#pragma unroll
        for (int mt = 0; mt < 4; mt++)
#pragma unroll
            for (int nt = 0; nt < 4; nt++)
                acc[mt][nt] = (f32x4v){0.f, 0.f, 0.f, 0.f};

        for (int kb = 0; kb < 8; kb++) {
            const int ko = kb * 32 + lrow * 8;
            bf16x8 af[4], bf[4];
#pragma unroll
            for (int mt = 0; mt < 4; mt++)
                af[mt] = *(const bf16x8*)&hea[(mt * 16 + lcol) * 264 + ko];
#pragma unroll
            for (int nt = 0; nt < 4; nt++)
                bf[nt] = *(const bf16x8*)&WxT[(size_t)(wcol + nt * 16 + lcol) * 256 + ko];
#pragma unroll
            for (int mt = 0; mt < 4; mt++)
#pragma unroll
                for (int nt = 0; nt < 4; nt++)
                    acc[mt][nt] = __builtin_amdgcn_mfma_f32_16x16x32_bf16(
                        af[mt], bf[nt], acc[mt][nt], 0, 0, 0);
        }

        // ---- epilogue: tanh + cs/dv accumulation
#pragma unroll
        for (int mt = 0; mt < 4; mt++) {
#pragma unroll
            for (int reg = 0; reg < 4; reg++) {
                int row = mt * 16 + lrow * 4 + reg;
                float4 xv = xds[row];
#pragma unroll
                for (int nt = 0; nt < 4; nt++) {
                    float coeff = tanh_fast(acc[mt][nt][reg]);
                    float cw = coeff * wv_l[nt];
                    cs[nt][0] += xv.x * coeff; cs[nt][1] += xv.y * coeff; cs[nt][2] += xv.z * coeff;
                    dv[0] += xv.x * cw; dv[1] += xv.y * cw; dv[2] += xv.z * cw;
                }
            }
        }
        __syncthreads();   // protect hea/xds before next pass staging
    }

    // h_e: column tid fully owned
    h_e[(size_t)bi * CC + tid] = he_acc;

    // reduce cs over the 4 row-group lanes (xor 16, 32)
#pragma unroll
    for (int nt = 0; nt < 4; nt++)
#pragma unroll
        for (int t = 0; t < 3; t++) {
            cs[nt][t] += __shfl_xor(cs[nt][t], 16, 64);
            cs[nt][t] += __shfl_xor(cs[nt][t], 32, 64);
        }
    if (lrow == 0) {
        const float invn = 1.f / (float)NN;
#pragma unroll
        for (int nt = 0; nt < 4; nt++) {
            int col = wcol + nt * 16 + lcol;
            float m0 = cs[nt][0] * invn, m1 = cs[nt][1] * invn, m2 = cs[nt][2] * invn;
            comb_norm[(size_t)bi * CC + col] = m0 * m0 + m1 * m1 + m2 * m2;
        }
    }

    // dv: full wave reduce then cross-wave via LDS
#pragma unroll
    for (int t = 0; t < 3; t++)
#pragma unroll
        for (int off = 32; off >= 1; off >>= 1)
            dv[t] += __shfl_xor(dv[t], off, 64);
    if (l == 0) {
        dvbuf[w][0] = dv[0]; dvbuf[w][1] = dv[1]; dvbuf[w][2] = dv[2];
    }
    __syncthreads();
    if (tid < 3) {
        float ssum = dvbuf[0][tid] + dvbuf[1][tid] + dvbuf[2][tid] + dvbuf[3][tid];
        delta_v[(size_t)bi * 3 + tid] = ssum * (1.f / (float)NN);
    }
}

// ---------------------------------------------------------------------------
// K4: node MLPs + velocity/position update (round-1 verified).
// ---------------------------------------------------------------------------
__global__ __launch_bounds__(64) void k4_node(
    const float* __restrict__ h, const float* __restrict__ x, const float* __restrict__ v,
    const float* __restrict__ h_e, const float* __restrict__ comb_norm,
    const float* __restrict__ delta_v,
    const float* __restrict__ Wp1, const float* __restrict__ bp1,
    const float* __restrict__ Wp2, const float* __restrict__ bp2,
    const float* __restrict__ Wn1, const float* __restrict__ bn1,
    const float* __restrict__ Wn2, const float* __restrict__ bn2,
    const float* __restrict__ Wvel1, const float* __restrict__ bvel1,
    const float* __restrict__ Wvel2,
    float* __restrict__ out)
{
    __shared__ float cn[CC];
    __shared__ float inb[FF + CC + HH];
    __shared__ float tmp[HH];
    __shared__ float hn[HH];

    const int bi = blockIdx.x;
    const int t = threadIdx.x;

#pragma unroll
    for (int r = 0; r < 4; r++) {
        cn[r * 64 + t] = comb_norm[(size_t)bi * CC + r * 64 + t];
        inb[FF + r * 64 + t] = h_e[(size_t)bi * CC + r * 64 + t];
    }
    inb[t] = h[(size_t)bi * FF + t];
    __syncthreads();

    float acc = bp1[t];
#pragma unroll 8
    for (int k = 0; k < CC; k++) acc += cn[k] * Wp1[k * HH + t];
    tmp[t] = siluf(acc);
    __syncthreads();
    acc = bp2[t];
#pragma unroll 8
    for (int k = 0; k < HH; k++) acc += tmp[k] * Wp2[k * HH + t];
    inb[FF + CC + t] = siluf(acc);
    __syncthreads();

    acc = bn1[t];
#pragma unroll 8
    for (int k = 0; k < FF + CC + HH; k++) acc += inb[k] * Wn1[k * HH + t];
    float n1v = siluf(acc);
    __syncthreads();
    tmp[t] = n1v;
    __syncthreads();
    acc = bn2[t];
#pragma unroll 8
    for (int k = 0; k < HH; k++) acc += tmp[k] * Wn2[k * FF + t];
    float hnew = inb[t] + siluf(acc);
    hn[t] = hnew;
    out[(size_t)bi * FF + t] = hnew;
    __syncthreads();

    acc = bvel1[t];
#pragma unroll 8
    for (int k = 0; k < HH; k++) acc += hn[k] * Wvel1[k * HH + t];
    float val = siluf(acc) * Wvel2[t];
#pragma unroll
    for (int off = 32; off >= 1; off >>= 1) val += __shfl_xor(val, off, 64);
    float vscale = 2.f * sigmoidf_(val);

    if (t < 3) {
        float vv = v[(size_t)bi * 3 + t];
        float vn = delta_v[(size_t)bi * 3 + t] + vscale * vv;
        out[32768 + (size_t)bi * 3 + t] = x[(size_t)bi * 3 + t] + vn;  // x_new
        out[34304 + (size_t)bi * 3 + t] = vn;                           // v_new
    }
}

// ---------------------------------------------------------------------------
extern "C" void kernel_launch(void* const* d_in, const int* in_sizes, int n_in,
                              void* d_out, int out_size, void* d_ws, size_t ws_size,
                              hipStream_t stream)
{
    const float* h        = (const float*)d_in[0];
    const float* x        = (const float*)d_in[1];
    const float* v        = (const float*)d_in[2];
    const float* means    = (const float*)d_in[3];
    const float* betas    = (const float*)d_in[4];
    const float* W_in     = (const float*)d_in[5];
    const float* b_in     = (const float*)d_in[6];
    const float* W_o1     = (const float*)d_in[7];
    const float* b_o1     = (const float*)d_in[8];
    const float* W_o2     = (const float*)d_in[9];
    const float* b_o2     = (const float*)d_in[10];
    const float* Ws       = (const float*)d_in[11];
    const float* bs       = (const float*)d_in[12];
    const float* log_gamma= (const float*)d_in[13];
    const float* Wx       = (const float*)d_in[14];
    const float* Wp1      = (const float*)d_in[15];
    const float* bp1      = (const float*)d_in[16];
    const float* Wp2      = (const float*)d_in[17];
    const float* bp2      = (const float*)d_in[18];
    const float* Wn1      = (const float*)d_in[19];
    const float* bn1      = (const float*)d_in[20];
    const float* Wn2      = (const float*)d_in[21];
    const float* bn2      = (const float*)d_in[22];
    const float* Wv_mix   = (const float*)d_in[23];
    const float* Wvel1    = (const float*)d_in[24];
    const float* bvel1    = (const float*)d_in[25];
    const float* Wvel2    = (const float*)d_in[26];

    float* ws = (float*)d_ws;
    float* norm_g    = ws;                 // 131072
    float* he_mtx    = ws + 131072;        // 8388608
    float* sem_logit = ws + 8519680;       // 524288 (WxT bf16 aliased here after k2)
    float* comb_att  = ws + 9043968;       // 524288 (UVPQ aliased here pre-k2)
    float* h_e       = ws + 9568256;       // 131072
    float* comb_norm = ws + 9699328;       // 131072
    float* delta_v   = ws + 9830400;       // 1536

    // U,V,P,Q live in the comb_att region: dead before k2 writes comb_att.
    float* U = comb_att;                   // 512*64
    float* V = comb_att + 32768;
    float* P = comb_att + 65536;
    float* Q = comb_att + 98304;

    // WxT bf16 lives in the sem_logit region: sem_logit is dead after k2,
    // and k0b runs after k2, so no liveness conflict.
    unsigned short* WxT = (unsigned short*)sem_logit;

    k0_node_pre<<<dim3(BN), dim3(64), 0, stream>>>(
        h, W_in, b_in, W_o1, b_o1, U, V, P, Q);

    k1_edge<<<dim3(NPAIR / 4), dim3(256), 0, stream>>>(
        x, means, betas, U, V, P, Q, W_o1, W_o2, b_o2, Ws, bs,
        he_mtx, sem_logit, norm_g);

    k2_attn<<<dim3(BN), dim3(256), 0, stream>>>(norm_g, sem_logit, log_gamma, comb_att);

    k0b_wxt<<<dim3(256), dim3(256), 0, stream>>>(Wx, WxT);

    k3_spatial<<<dim3(BN), dim3(256), 0, stream>>>(
        he_mtx, comb_att, x, norm_g, WxT, Wv_mix, h_e, comb_norm, delta_v);

    k4_node<<<dim3(BN), dim3(64), 0, stream>>>(
        h, x, v, h_e, comb_norm, delta_v,
        Wp1, bp1, Wp2, bp2, Wn1, bn1, Wn2, bn2, Wvel1, bvel1, Wvel2,
        (float*)d_out);
}

// Round 5
// 285.337 us; speedup vs baseline: 3.5524x; 1.4919x over previous
//
#include <hip/hip_runtime.h>
#include <math.h>

#define NB 2
#define NN 256
#define FF 64
#define HH 64
#define NHEADS 4
#define KK 50
#define CC 256

constexpr int BN = NB * NN;          // 512
constexpr int NPAIR = NB * NN * NN;  // 131072

typedef __attribute__((ext_vector_type(8))) short bf16x8;
typedef __attribute__((ext_vector_type(4))) float f32x4v;

__device__ __forceinline__ float siluf(float v) { return v / (1.f + __expf(-v)); }
__device__ __forceinline__ float sigmoidf_(float v) { return 1.f / (1.f + __expf(-v)); }
__device__ __forceinline__ float tanh_fast(float x) {
    x = fminf(fmaxf(x, -15.f), 15.f);
    float e = __expf(2.f * x);
    return (e - 1.f) / (e + 1.f);
}
__device__ __forceinline__ unsigned short f2bf(float f) {
    union { float f; unsigned u; } v; v.f = f;
    unsigned r = v.u + 0x7fffu + ((v.u >> 16) & 1u);
    return (unsigned short)(r >> 16);
}
__device__ __forceinline__ float bf2f(short s) {
    union { unsigned u; float f; } v;
    v.u = ((unsigned)(unsigned short)s) << 16;
    return v.f;
}

// ---------------------------------------------------------------------------
// K0: per-node precompute (U,V from W_in halves; P,Q from W_o1 halves).
// ---------------------------------------------------------------------------
__global__ __launch_bounds__(64) void k0_node_pre(
    const float* __restrict__ h,
    const float* __restrict__ W_in, const float* __restrict__ b_in,
    const float* __restrict__ W_o1, const float* __restrict__ b_o1,
    float* __restrict__ U, float* __restrict__ V,
    float* __restrict__ P, float* __restrict__ Q)
{
    __shared__ float hh[64];
    const int bn = blockIdx.x;
    const int t = threadIdx.x;
    hh[t] = h[(size_t)bn * FF + t];
    __syncthreads();

    float accP = b_o1[t], accQ = 0.f;
#pragma unroll 8
    for (int k = 0; k < 64; k++) {
        float hv = hh[k];
        accP += hv * W_o1[k * HH + t];
        accQ += hv * W_o1[(64 + k) * HH + t];
    }
    P[(size_t)bn * 64 + t] = accP;
    Q[(size_t)bn * 64 + t] = accQ;

    if (t < KK) {
        float aU = b_in[t], aV = 0.f;
#pragma unroll 8
        for (int k = 0; k < 64; k++) {
            float hv = hh[k];
            aU += hv * W_in[k * KK + t];
            aV += hv * W_in[(64 + k) * KK + t];
        }
        U[(size_t)bn * 64 + t] = aU;
        V[(size_t)bn * 64 + t] = aV;
    }
}

// ---------------------------------------------------------------------------
// K0c: build bf16 B^T tables for k1's two MFMA GEMMs.
//   Wo1T[n][k] (64x64): k<50 -> W_o1[(128+k)*64+n]; k==50 -> W_o1[178*64+n]; else 0
//   Wo2T[n][k] (64x64): W_o2[k*64+n]
// ---------------------------------------------------------------------------
__global__ __launch_bounds__(256) void k0c_wtrans(
    const float* __restrict__ W_o1, const float* __restrict__ W_o2,
    unsigned short* __restrict__ Wo1T, unsigned short* __restrict__ Wo2T)
{
    int idx = blockIdx.x * 256 + threadIdx.x;   // 4096 total
    int n = idx >> 6, k = idx & 63;
    float v1 = (k < KK) ? W_o1[(128 + k) * HH + n]
             : (k == KK) ? W_o1[178 * HH + n] : 0.f;
    Wo1T[idx] = f2bf(v1);
    Wo2T[idx] = f2bf(W_o2[k * HH + n]);
}

// ---------------------------------------------------------------------------
// K0b: Wx [k][n] fp32 -> WxT [n][k] bf16 (for k3). Runs AFTER k2.
// ---------------------------------------------------------------------------
__global__ __launch_bounds__(256) void k0b_wxt(
    const float* __restrict__ Wx, unsigned short* __restrict__ WxT)
{
    int idx = blockIdx.x * 256 + threadIdx.x;   // 65536 total
    int n = idx >> 8, k = idx & 255;
    WxT[idx] = f2bf(Wx[k * 256 + n]);
}

// ---------------------------------------------------------------------------
// K1: edge model via bf16 MFMA. One block per (b,i); 256 thr = 4 waves.
//   A1[256 j][72] bf16: cols 0..49 = rbf*hk, 50 = nrm, 51..63 = 0
//   GEMM1 (M256,K64,N64): + P[j]+Q[i], silu -> A2 bf16
//   GEMM2 (M256,K64,N64): -> he (fp32 global + bf16 back into A1)
//   sem phase: thread=j, celu(he@Ws+bs) - eye
// Wave w owns output cols w*16..w*16+15. C layout: col=lane&15,
// row=quad*4+reg (m89-verified). Stride 72 shorts -> 2-way-free b128.
// ---------------------------------------------------------------------------
__global__ __launch_bounds__(256) void k1_edge_mfma(
    const float* __restrict__ x,
    const float* __restrict__ means, const float* __restrict__ betas,
    const float* __restrict__ U, const float* __restrict__ V,
    const float* __restrict__ P, const float* __restrict__ Q,
    const unsigned short* __restrict__ Wo1T, const unsigned short* __restrict__ Wo2T,
    const float* __restrict__ Ws, const float* __restrict__ bs,
    float* __restrict__ he_mtx, float* __restrict__ sem_logit,
    float* __restrict__ norm_g)
{
    __shared__ __align__(16) unsigned short A1[256 * 72];   // 36 KB
    __shared__ __align__(16) unsigned short A2[256 * 72];   // 36 KB
    __shared__ float nrm_s[256];
    __shared__ float en_s[256];

    const int tid = threadIdx.x;
    const int l = tid & 63;
    const int w = tid >> 6;
    const int lcol = l & 15;
    const int quad = l >> 4;
    const int bi = blockIdx.x;
    const int b = bi >> 8;
    const int i = bi & 255;
    const float* xb = x + (size_t)b * NN * 3;

    // ---- phase 0: per-j geometry (thread = j)
    {
        int j = tid;
        float dx0 = xb[j * 3 + 0] - xb[i * 3 + 0];
        float dx1 = xb[j * 3 + 1] - xb[i * 3 + 1];
        float dx2 = xb[j * 3 + 2] - xb[i * 3 + 2];
        float d2 = dx0 * dx0 + dx1 * dx1 + dx2 * dx2;
        float nrm = sqrtf(fmaxf(d2, 0.f) + 1e-5f);
        nrm_s[j] = nrm;
        en_s[j] = __expf(-nrm);
        norm_g[(size_t)bi * NN + j] = nrm;
    }
    __syncthreads();

    // ---- phase 1: stage A1 = [rbf*hk | nrm | 0] bf16.
    // Wave handles one j per iteration (lane = k), fully coalesced U loads.
    {
        const int k = tid & 63;
        const int jg = tid >> 6;
        const bool kv = (k < KK);
        const float v_ik = kv ? V[((size_t)b * NN + i) * 64 + k] : 0.f;
        const float mean_k = kv ? means[k] : 0.f;
        const float beta_k = kv ? betas[k] : 0.f;
        for (int jj = 0; jj < 64; jj++) {
            int j = jj * 4 + jg;
            float u = kv ? U[((size_t)b * NN + j) * 64 + k] : 0.f;
            float hk = u + v_ik;
            float e = en_s[j] - mean_k;
            float val = __expf(-beta_k * e * e) * hk;   // k>=50: beta=0, hk=0 -> 0
            if (k == KK) val = nrm_s[j];
            A1[j * 72 + k] = f2bf(val);
        }
    }
    __syncthreads();

    const int col = w * 16 + lcol;       // output channel owned by this lane

    // ---- phase 2: GEMM1 -> s1 = silu(acc + P[j] + Q[i]) -> A2 bf16
    {
        const float q_val = Q[((size_t)b * NN + i) * 64 + col];
        f32x4v acc[16];
#pragma unroll
        for (int mt = 0; mt < 16; mt++) acc[mt] = (f32x4v){0.f, 0.f, 0.f, 0.f};

#pragma unroll
        for (int kb = 0; kb < 2; kb++) {
            const int ko = kb * 32 + quad * 8;
            bf16x8 bfrag = *(const bf16x8*)&Wo1T[col * 64 + ko];
#pragma unroll
            for (int mt = 0; mt < 16; mt++) {
                bf16x8 afrag = *(const bf16x8*)&A1[(mt * 16 + lcol) * 72 + ko];
                acc[mt] = __builtin_amdgcn_mfma_f32_16x16x32_bf16(afrag, bfrag, acc[mt], 0, 0, 0);
            }
        }

#pragma unroll
        for (int mt = 0; mt < 16; mt++) {
#pragma unroll
            for (int reg = 0; reg < 4; reg++) {
                int j = mt * 16 + quad * 4 + reg;
                float pv = P[((size_t)b * NN + j) * 64 + col];
                float s1v = siluf(acc[mt][reg] + pv + q_val);
                A2[j * 72 + col] = f2bf(s1v);
            }
        }
    }
    __syncthreads();

    // ---- phase 3: GEMM2 -> he; write fp32 global + bf16 into A1
    {
        f32x4v acc[16];
#pragma unroll
        for (int mt = 0; mt < 16; mt++) acc[mt] = (f32x4v){0.f, 0.f, 0.f, 0.f};

#pragma unroll
        for (int kb = 0; kb < 2; kb++) {
            const int ko = kb * 32 + quad * 8;
            bf16x8 bfrag = *(const bf16x8*)&Wo2T[col * 64 + ko];
#pragma unroll
            for (int mt = 0; mt < 16; mt++) {
                bf16x8 afrag = *(const bf16x8*)&A2[(mt * 16 + lcol) * 72 + ko];
                acc[mt] = __builtin_amdgcn_mfma_f32_16x16x32_bf16(afrag, bfrag, acc[mt], 0, 0, 0);
            }
        }

#pragma unroll
        for (int mt = 0; mt < 16; mt++) {
#pragma unroll
            for (int reg = 0; reg < 4; reg++) {
                int j = mt * 16 + quad * 4 + reg;
                float hev = acc[mt][reg];
                he_mtx[((size_t)bi * NN + j) * HH + col] = hev;
                A1[j * 72 + col] = f2bf(hev);
            }
        }
    }
    __syncthreads();

    // ---- phase 4: sem logits (thread = j): celu(he @ Ws + bs, 2) - 1e5*eye
    {
        int j = tid;
        const float4* Ws4 = (const float4*)Ws;   // row ch -> 4 heads
        float a0 = bs[0], a1 = bs[1], a2 = bs[2], a3 = bs[3];
#pragma unroll
        for (int c8 = 0; c8 < 64; c8 += 8) {
            bf16x8 hv8 = *(const bf16x8*)&A1[j * 72 + c8];
#pragma unroll
            for (int t = 0; t < 8; t++) {
                float hv = bf2f(hv8[t]);
                float4 wsv = Ws4[c8 + t];
                a0 += hv * wsv.x; a1 += hv * wsv.y;
                a2 += hv * wsv.z; a3 += hv * wsv.w;
            }
        }
        float4 out;
        out.x = a0 > 0.f ? a0 : 2.f * expm1f(0.5f * a0);
        out.y = a1 > 0.f ? a1 : 2.f * expm1f(0.5f * a1);
        out.z = a2 > 0.f ? a2 : 2.f * expm1f(0.5f * a2);
        out.w = a3 > 0.f ? a3 : 2.f * expm1f(0.5f * a3);
        if (i == j) { out.x -= 1e5f; out.y -= 1e5f; out.z -= 1e5f; out.w -= 1e5f; }
        ((float4*)sem_logit)[(size_t)bi * NN + j] = out;
    }
}

// ---------------------------------------------------------------------------
// K2: the three softmaxes over j (round-1 verified).
// ---------------------------------------------------------------------------
__device__ __forceinline__ float4 block_max4(float4 v, float4* buf) {
    int tid = threadIdx.x;
    buf[tid] = v;
    __syncthreads();
    for (int s = 128; s > 0; s >>= 1) {
        if (tid < s) {
            float4 o = buf[tid + s], m = buf[tid];
            m.x = fmaxf(m.x, o.x); m.y = fmaxf(m.y, o.y);
            m.z = fmaxf(m.z, o.z); m.w = fmaxf(m.w, o.w);
            buf[tid] = m;
        }
        __syncthreads();
    }
    float4 r = buf[0];
    __syncthreads();
    return r;
}

__device__ __forceinline__ float4 block_sum4(float4 v, float4* buf) {
    int tid = threadIdx.x;
    buf[tid] = v;
    __syncthreads();
    for (int s = 128; s > 0; s >>= 1) {
        if (tid < s) {
            float4 o = buf[tid + s], m = buf[tid];
            m.x += o.x; m.y += o.y; m.z += o.z; m.w += o.w;
            buf[tid] = m;
        }
        __syncthreads();
    }
    float4 r = buf[0];
    __syncthreads();
    return r;
}

__global__ __launch_bounds__(256) void k2_attn(
    const float* __restrict__ norm_g, const float* __restrict__ sem_logit,
    const float* __restrict__ log_gamma, float* __restrict__ comb_att)
{
    __shared__ float4 buf[256];
    const int bi = blockIdx.x;
    const int i = bi & 255;
    const int j = threadIdx.x;
    const size_t base = (size_t)bi * NN + j;

    float g0 = __expf(log_gamma[0]);
    float g1 = __expf(log_gamma[1]);
    float g2 = __expf(log_gamma[2]);
    float g3 = __expf(log_gamma[3]);

    float nrm = norm_g[base];
    float pen = (j == i) ? 1e5f : 0.f;
    float nl = -(nrm + pen);
    float4 el = make_float4(nl * g0, nl * g1, nl * g2, nl * g3);
    float4 sl = ((const float4*)sem_logit)[base];

    float4 m = block_max4(el, buf);
    float4 ev = make_float4(__expf(el.x - m.x), __expf(el.y - m.y),
                            __expf(el.z - m.z), __expf(el.w - m.w));
    float4 sum = block_sum4(ev, buf);
    float4 eucl = make_float4(ev.x / sum.x, ev.y / sum.y, ev.z / sum.z, ev.w / sum.w);

    m = block_max4(sl, buf);
    float4 sv = make_float4(__expf(sl.x - m.x), __expf(sl.y - m.y),
                            __expf(sl.z - m.z), __expf(sl.w - m.w));
    sum = block_sum4(sv, buf);
    float4 sem = make_float4(sv.x / sum.x, sv.y / sum.y, sv.z / sum.z, sv.w / sum.w);

    float4 cl = make_float4(eucl.x * sem.x, eucl.y * sem.y, eucl.z * sem.z, eucl.w * sem.w);
    m = block_max4(cl, buf);
    float4 cv = make_float4(__expf(cl.x - m.x), __expf(cl.y - m.y),
                            __expf(cl.z - m.z), __expf(cl.w - m.w));
    sum = block_sum4(cv, buf);
    float4 ca = make_float4(cv.x / sum.x, cv.y / sum.y, cv.z / sum.z, cv.w / sum.w);

    ((float4*)comb_att)[base] = ca;
}

// ---------------------------------------------------------------------------
// K3: bf16 MFMA spatial attention (round-4 verified).
// ---------------------------------------------------------------------------
__global__ __launch_bounds__(256) void k3_spatial(
    const float* __restrict__ he_mtx, const float* __restrict__ comb_att,
    const float* __restrict__ x, const float* __restrict__ norm_g,
    const unsigned short* __restrict__ WxT, const float* __restrict__ Wv_mix,
    float* __restrict__ h_e, float* __restrict__ comb_norm,
    float* __restrict__ delta_v)
{
    __shared__ unsigned short hea[64 * 264];   // 33 KB
    __shared__ float4 xds[64];                 // 1 KB
    __shared__ float dvbuf[4][3];

    const int tid = threadIdx.x;
    const int l = tid & 63;
    const int w = tid >> 6;
    const int lrow = l >> 4;        // quad 0..3
    const int lcol = l & 15;
    const int wcol = w * 64;
    const int bi = blockIdx.x;
    const int b = bi >> 8;
    const int i = bi & 255;

    const float* xb = x + (size_t)b * NN * 3;
    const float xi0 = xb[i * 3 + 0], xi1 = xb[i * 3 + 1], xi2 = xb[i * 3 + 2];

    float wv_l[4];
#pragma unroll
    for (int nt = 0; nt < 4; nt++) wv_l[nt] = Wv_mix[wcol + nt * 16 + lcol];

    float cs[4][3] = {{0.f,0.f,0.f},{0.f,0.f,0.f},{0.f,0.f,0.f},{0.f,0.f,0.f}};
    float dv[3] = {0.f, 0.f, 0.f};
    float he_acc = 0.f;

    const int hh_idx = tid >> 2;
    const int hd_idx = tid & 3;

    for (int pass = 0; pass < 4; pass++) {
        const int jt = pass * 64;

        for (int jj = 0; jj < 64; jj++) {
            int j = jt + jj;
            float hv = he_mtx[((size_t)bi * NN + j) * HH + hh_idx];
            float av = comb_att[((size_t)bi * NN + j) * 4 + hd_idx];
            float pval = hv * av;
            he_acc += pval;
            hea[jj * 264 + tid] = f2bf(pval);
        }
        if (tid < 64) {
            int j = jt + tid;
            float nrm = norm_g[(size_t)bi * NN + j];
            float inv = 1.f / (nrm + 1e-5f);
            xds[tid] = make_float4((xb[j * 3 + 0] - xi0) * inv,
                                   (xb[j * 3 + 1] - xi1) * inv,
                                   (xb[j * 3 + 2] - xi2) * inv, 0.f);
        }
        __syncthreads();

        f32x4v acc[4][4];
#pragma unroll
        for (int mt = 0; mt < 4; mt++)
#pragma unroll
            for (int nt = 0; nt < 4; nt++)
                acc[mt][nt] = (f32x4v){0.f, 0.f, 0.f, 0.f};

        for (int kb = 0; kb < 8; kb++) {
            const int ko = kb * 32 + lrow * 8;
            bf16x8 af[4], bf[4];
#pragma unroll
            for (int mt = 0; mt < 4; mt++)
                af[mt] = *(const bf16x8*)&hea[(mt * 16 + lcol) * 264 + ko];
#pragma unroll
            for (int nt = 0; nt < 4; nt++)
                bf[nt] = *(const bf16x8*)&WxT[(size_t)(wcol + nt * 16 + lcol) * 256 + ko];
#pragma unroll
            for (int mt = 0; mt < 4; mt++)
#pragma unroll
                for (int nt = 0; nt < 4; nt++)
                    acc[mt][nt] = __builtin_amdgcn_mfma_f32_16x16x32_bf16(
                        af[mt], bf[nt], acc[mt][nt], 0, 0, 0);
        }

#pragma unroll
        for (int mt = 0; mt < 4; mt++) {
#pragma unroll
            for (int reg = 0; reg < 4; reg++) {
                int row = mt * 16 + lrow * 4 + reg;
                float4 xv = xds[row];
#pragma unroll
                for (int nt = 0; nt < 4; nt++) {
                    float coeff = tanh_fast(acc[mt][nt][reg]);
                    float cw = coeff * wv_l[nt];
                    cs[nt][0] += xv.x * coeff; cs[nt][1] += xv.y * coeff; cs[nt][2] += xv.z * coeff;
                    dv[0] += xv.x * cw; dv[1] += xv.y * cw; dv[2] += xv.z * cw;
                }
            }
        }
        __syncthreads();
    }

    h_e[(size_t)bi * CC + tid] = he_acc;

#pragma unroll
    for (int nt = 0; nt < 4; nt++)
#pragma unroll
        for (int t = 0; t < 3; t++) {
            cs[nt][t] += __shfl_xor(cs[nt][t], 16, 64);
            cs[nt][t] += __shfl_xor(cs[nt][t], 32, 64);
        }
    if (lrow == 0) {
        const float invn = 1.f / (float)NN;
#pragma unroll
        for (int nt = 0; nt < 4; nt++) {
            int colx = wcol + nt * 16 + lcol;
            float m0 = cs[nt][0] * invn, m1 = cs[nt][1] * invn, m2 = cs[nt][2] * invn;
            comb_norm[(size_t)bi * CC + colx] = m0 * m0 + m1 * m1 + m2 * m2;
        }
    }

#pragma unroll
    for (int t = 0; t < 3; t++)
#pragma unroll
        for (int off = 32; off >= 1; off >>= 1)
            dv[t] += __shfl_xor(dv[t], off, 64);
    if (l == 0) {
        dvbuf[w][0] = dv[0]; dvbuf[w][1] = dv[1]; dvbuf[w][2] = dv[2];
    }
    __syncthreads();
    if (tid < 3) {
        float ssum = dvbuf[0][tid] + dvbuf[1][tid] + dvbuf[2][tid] + dvbuf[3][tid];
        delta_v[(size_t)bi * 3 + tid] = ssum * (1.f / (float)NN);
    }
}

// ---------------------------------------------------------------------------
// K4: node MLPs + velocity/position update (round-1 verified).
// ---------------------------------------------------------------------------
__global__ __launch_bounds__(64) void k4_node(
    const float* __restrict__ h, const float* __restrict__ x, const float* __restrict__ v,
    const float* __restrict__ h_e, const float* __restrict__ comb_norm,
    const float* __restrict__ delta_v,
    const float* __restrict__ Wp1, const float* __restrict__ bp1,
    const float* __restrict__ Wp2, const float* __restrict__ bp2,
    const float* __restrict__ Wn1, const float* __restrict__ bn1,
    const float* __restrict__ Wn2, const float* __restrict__ bn2,
    const float* __restrict__ Wvel1, const float* __restrict__ bvel1,
    const float* __restrict__ Wvel2,
    float* __restrict__ out)
{
    __shared__ float cn[CC];
    __shared__ float inb[FF + CC + HH];
    __shared__ float tmp[HH];
    __shared__ float hn[HH];

    const int bi = blockIdx.x;
    const int t = threadIdx.x;

#pragma unroll
    for (int r = 0; r < 4; r++) {
        cn[r * 64 + t] = comb_norm[(size_t)bi * CC + r * 64 + t];
        inb[FF + r * 64 + t] = h_e[(size_t)bi * CC + r * 64 + t];
    }
    inb[t] = h[(size_t)bi * FF + t];
    __syncthreads();

    float acc = bp1[t];
#pragma unroll 8
    for (int k = 0; k < CC; k++) acc += cn[k] * Wp1[k * HH + t];
    tmp[t] = siluf(acc);
    __syncthreads();
    acc = bp2[t];
#pragma unroll 8
    for (int k = 0; k < HH; k++) acc += tmp[k] * Wp2[k * HH + t];
    inb[FF + CC + t] = siluf(acc);
    __syncthreads();

    acc = bn1[t];
#pragma unroll 8
    for (int k = 0; k < FF + CC + HH; k++) acc += inb[k] * Wn1[k * HH + t];
    float n1v = siluf(acc);
    __syncthreads();
    tmp[t] = n1v;
    __syncthreads();
    acc = bn2[t];
#pragma unroll 8
    for (int k = 0; k < HH; k++) acc += tmp[k] * Wn2[k * FF + t];
    float hnew = inb[t] + siluf(acc);
    hn[t] = hnew;
    out[(size_t)bi * FF + t] = hnew;
    __syncthreads();

    acc = bvel1[t];
#pragma unroll 8
    for (int k = 0; k < HH; k++) acc += hn[k] * Wvel1[k * HH + t];
    float val = siluf(acc) * Wvel2[t];
#pragma unroll
    for (int off = 32; off >= 1; off >>= 1) val += __shfl_xor(val, off, 64);
    float vscale = 2.f * sigmoidf_(val);

    if (t < 3) {
        float vv = v[(size_t)bi * 3 + t];
        float vn = delta_v[(size_t)bi * 3 + t] + vscale * vv;
        out[32768 + (size_t)bi * 3 + t] = x[(size_t)bi * 3 + t] + vn;  // x_new
        out[34304 + (size_t)bi * 3 + t] = vn;                           // v_new
    }
}

// ---------------------------------------------------------------------------
extern "C" void kernel_launch(void* const* d_in, const int* in_sizes, int n_in,
                              void* d_out, int out_size, void* d_ws, size_t ws_size,
                              hipStream_t stream)
{
    const float* h        = (const float*)d_in[0];
    const float* x        = (const float*)d_in[1];
    const float* v        = (const float*)d_in[2];
    const float* means    = (const float*)d_in[3];
    const float* betas    = (const float*)d_in[4];
    const float* W_in     = (const float*)d_in[5];
    const float* b_in     = (const float*)d_in[6];
    const float* W_o1     = (const float*)d_in[7];
    const float* b_o1     = (const float*)d_in[8];
    const float* W_o2     = (const float*)d_in[9];
    const float* b_o2     = (const float*)d_in[10];
    const float* Ws       = (const float*)d_in[11];
    const float* bs       = (const float*)d_in[12];
    const float* log_gamma= (const float*)d_in[13];
    const float* Wx       = (const float*)d_in[14];
    const float* Wp1      = (const float*)d_in[15];
    const float* bp1      = (const float*)d_in[16];
    const float* Wp2      = (const float*)d_in[17];
    const float* bp2      = (const float*)d_in[18];
    const float* Wn1      = (const float*)d_in[19];
    const float* bn1      = (const float*)d_in[20];
    const float* Wn2      = (const float*)d_in[21];
    const float* bn2      = (const float*)d_in[22];
    const float* Wv_mix   = (const float*)d_in[23];
    const float* Wvel1    = (const float*)d_in[24];
    const float* bvel1    = (const float*)d_in[25];
    const float* Wvel2    = (const float*)d_in[26];

    float* ws = (float*)d_ws;
    float* norm_g    = ws;                 // 131072
    float* he_mtx    = ws + 131072;        // 8388608
    float* sem_logit = ws + 8519680;       // 524288 (WxT bf16 aliased after k2)
    float* comb_att  = ws + 9043968;       // 524288 (UVPQ + Wo1T/Wo2T aliased pre-k2)
    float* h_e       = ws + 9568256;       // 131072
    float* comb_norm = ws + 9699328;       // 131072
    float* delta_v   = ws + 9830400;       // 1536

    // Pre-k2 aliases in the comb_att region (dead until k2 writes it):
    float* U = comb_att;                   // 512*64
    float* V = comb_att + 32768;
    float* P = comb_att + 65536;
    float* Q = comb_att + 98304;
    unsigned short* Wo1T = (unsigned short*)(comb_att + 131072);  // 4096 shorts
    unsigned short* Wo2T = (unsigned short*)(comb_att + 133120);  // 4096 shorts

    // WxT bf16 aliases sem_logit (dead after k2; k0b runs after k2).
    unsigned short* WxT = (unsigned short*)sem_logit;

    k0_node_pre<<<dim3(BN), dim3(64), 0, stream>>>(
        h, W_in, b_in, W_o1, b_o1, U, V, P, Q);

    k0c_wtrans<<<dim3(16), dim3(256), 0, stream>>>(W_o1, W_o2, Wo1T, Wo2T);

    k1_edge_mfma<<<dim3(BN), dim3(256), 0, stream>>>(
        x, means, betas, U, V, P, Q, Wo1T, Wo2T, Ws, bs,
        he_mtx, sem_logit, norm_g);

    k2_attn<<<dim3(BN), dim3(256), 0, stream>>>(norm_g, sem_logit, log_gamma, comb_att);

    k0b_wxt<<<dim3(256), dim3(256), 0, stream>>>(Wx, WxT);

    k3_spatial<<<dim3(BN), dim3(256), 0, stream>>>(
        he_mtx, comb_att, x, norm_g, WxT, Wv_mix, h_e, comb_norm, delta_v);

    k4_node<<<dim3(BN), dim3(64), 0, stream>>>(
        h, x, v, h_e, comb_norm, delta_v,
        Wp1, bp1, Wp2, bp2, Wn1, bn1, Wn2, bn2, Wvel1, bvel1, Wvel2,
        (float*)d_out);
}

// Round 6
// 264.043 us; speedup vs baseline: 3.8388x; 1.0806x over previous
//
#include <hip/hip_runtime.h>
#include <math.h>

#define NB 2
#define NN 256
#define FF 64
#define HH 64
#define NHEADS 4
#define KK 50
#define CC 256

constexpr int BN = NB * NN;          // 512
constexpr int NPAIR = NB * NN * NN;  // 131072

typedef __attribute__((ext_vector_type(8))) short bf16x8;
typedef __attribute__((ext_vector_type(4))) float f32x4v;

__device__ __forceinline__ float siluf(float v) { return v / (1.f + __expf(-v)); }
__device__ __forceinline__ float sigmoidf_(float v) { return 1.f / (1.f + __expf(-v)); }
__device__ __forceinline__ float tanh_fast(float x) {
    x = fminf(fmaxf(x, -15.f), 15.f);
    float e = __expf(2.f * x);
    return (e - 1.f) / (e + 1.f);
}
__device__ __forceinline__ unsigned short f2bf(float f) {
    union { float f; unsigned u; } v; v.f = f;
    unsigned r = v.u + 0x7fffu + ((v.u >> 16) & 1u);
    return (unsigned short)(r >> 16);
}
__device__ __forceinline__ float bf2f(short s) {
    union { unsigned u; float f; } v;
    v.u = ((unsigned)(unsigned short)s) << 16;
    return v.f;
}

// ---------------------------------------------------------------------------
// K0: per-node precompute (U,V from W_in halves; P,Q from W_o1 halves).
// ---------------------------------------------------------------------------
__global__ __launch_bounds__(64) void k0_node_pre(
    const float* __restrict__ h,
    const float* __restrict__ W_in, const float* __restrict__ b_in,
    const float* __restrict__ W_o1, const float* __restrict__ b_o1,
    float* __restrict__ U, float* __restrict__ V,
    float* __restrict__ P, float* __restrict__ Q)
{
    __shared__ float hh[64];
    const int bn = blockIdx.x;
    const int t = threadIdx.x;
    hh[t] = h[(size_t)bn * FF + t];
    __syncthreads();

    float accP = b_o1[t], accQ = 0.f;
#pragma unroll 8
    for (int k = 0; k < 64; k++) {
        float hv = hh[k];
        accP += hv * W_o1[k * HH + t];
        accQ += hv * W_o1[(64 + k) * HH + t];
    }
    P[(size_t)bn * 64 + t] = accP;
    Q[(size_t)bn * 64 + t] = accQ;

    if (t < KK) {
        float aU = b_in[t], aV = 0.f;
#pragma unroll 8
        for (int k = 0; k < 64; k++) {
            float hv = hh[k];
            aU += hv * W_in[k * KK + t];
            aV += hv * W_in[(64 + k) * KK + t];
        }
        U[(size_t)bn * 64 + t] = aU;
        V[(size_t)bn * 64 + t] = aV;
    }
}

// ---------------------------------------------------------------------------
// K0c: build bf16 B^T tables for k1's two MFMA GEMMs.
// ---------------------------------------------------------------------------
__global__ __launch_bounds__(256) void k0c_wtrans(
    const float* __restrict__ W_o1, const float* __restrict__ W_o2,
    unsigned short* __restrict__ Wo1T, unsigned short* __restrict__ Wo2T)
{
    int idx = blockIdx.x * 256 + threadIdx.x;   // 4096 total
    int n = idx >> 6, k = idx & 63;
    float v1 = (k < KK) ? W_o1[(128 + k) * HH + n]
             : (k == KK) ? W_o1[178 * HH + n] : 0.f;
    Wo1T[idx] = f2bf(v1);
    Wo2T[idx] = f2bf(W_o2[k * HH + n]);
}

// ---------------------------------------------------------------------------
// K0b: Wx [k][n] fp32 -> WxT [n][k] bf16 (for k3). Runs AFTER k2.
// ---------------------------------------------------------------------------
__global__ __launch_bounds__(256) void k0b_wxt(
    const float* __restrict__ Wx, unsigned short* __restrict__ WxT)
{
    int idx = blockIdx.x * 256 + threadIdx.x;   // 65536 total
    int n = idx >> 8, k = idx & 255;
    WxT[idx] = f2bf(Wx[k * 256 + n]);
}

// ---------------------------------------------------------------------------
// K1: edge model via bf16 MFMA (round-5 verified).
// ---------------------------------------------------------------------------
__global__ __launch_bounds__(256) void k1_edge_mfma(
    const float* __restrict__ x,
    const float* __restrict__ means, const float* __restrict__ betas,
    const float* __restrict__ U, const float* __restrict__ V,
    const float* __restrict__ P, const float* __restrict__ Q,
    const unsigned short* __restrict__ Wo1T, const unsigned short* __restrict__ Wo2T,
    const float* __restrict__ Ws, const float* __restrict__ bs,
    float* __restrict__ he_mtx, float* __restrict__ sem_logit,
    float* __restrict__ norm_g)
{
    __shared__ __align__(16) unsigned short A1[256 * 72];   // 36 KB
    __shared__ __align__(16) unsigned short A2[256 * 72];   // 36 KB
    __shared__ float nrm_s[256];
    __shared__ float en_s[256];

    const int tid = threadIdx.x;
    const int l = tid & 63;
    const int w = tid >> 6;
    const int lcol = l & 15;
    const int quad = l >> 4;
    const int bi = blockIdx.x;
    const int b = bi >> 8;
    const int i = bi & 255;
    const float* xb = x + (size_t)b * NN * 3;

    // ---- phase 0: per-j geometry (thread = j)
    {
        int j = tid;
        float dx0 = xb[j * 3 + 0] - xb[i * 3 + 0];
        float dx1 = xb[j * 3 + 1] - xb[i * 3 + 1];
        float dx2 = xb[j * 3 + 2] - xb[i * 3 + 2];
        float d2 = dx0 * dx0 + dx1 * dx1 + dx2 * dx2;
        float nrm = sqrtf(fmaxf(d2, 0.f) + 1e-5f);
        nrm_s[j] = nrm;
        en_s[j] = __expf(-nrm);
        norm_g[(size_t)bi * NN + j] = nrm;
    }
    __syncthreads();

    // ---- phase 1: stage A1 = [rbf*hk | nrm | 0] bf16 (lane = k)
    {
        const int k = tid & 63;
        const int jg = tid >> 6;
        const bool kv = (k < KK);
        const float v_ik = kv ? V[((size_t)b * NN + i) * 64 + k] : 0.f;
        const float mean_k = kv ? means[k] : 0.f;
        const float beta_k = kv ? betas[k] : 0.f;
        for (int jj = 0; jj < 64; jj++) {
            int j = jj * 4 + jg;
            float u = kv ? U[((size_t)b * NN + j) * 64 + k] : 0.f;
            float hk = u + v_ik;
            float e = en_s[j] - mean_k;
            float val = __expf(-beta_k * e * e) * hk;   // k>=50: beta=0, hk=0 -> 0
            if (k == KK) val = nrm_s[j];
            A1[j * 72 + k] = f2bf(val);
        }
    }
    __syncthreads();

    const int col = w * 16 + lcol;       // output channel owned by this lane

    // ---- phase 2: GEMM1 -> s1 = silu(acc + P[j] + Q[i]) -> A2 bf16
    {
        const float q_val = Q[((size_t)b * NN + i) * 64 + col];
        f32x4v acc[16];
#pragma unroll
        for (int mt = 0; mt < 16; mt++) acc[mt] = (f32x4v){0.f, 0.f, 0.f, 0.f};

#pragma unroll
        for (int kb = 0; kb < 2; kb++) {
            const int ko = kb * 32 + quad * 8;
            bf16x8 bfrag = *(const bf16x8*)&Wo1T[col * 64 + ko];
#pragma unroll
            for (int mt = 0; mt < 16; mt++) {
                bf16x8 afrag = *(const bf16x8*)&A1[(mt * 16 + lcol) * 72 + ko];
                acc[mt] = __builtin_amdgcn_mfma_f32_16x16x32_bf16(afrag, bfrag, acc[mt], 0, 0, 0);
            }
        }

#pragma unroll
        for (int mt = 0; mt < 16; mt++) {
#pragma unroll
            for (int reg = 0; reg < 4; reg++) {
                int j = mt * 16 + quad * 4 + reg;
                float pv = P[((size_t)b * NN + j) * 64 + col];
                float s1v = siluf(acc[mt][reg] + pv + q_val);
                A2[j * 72 + col] = f2bf(s1v);
            }
        }
    }
    __syncthreads();

    // ---- phase 3: GEMM2 -> he; write fp32 global + bf16 into A1
    {
        f32x4v acc[16];
#pragma unroll
        for (int mt = 0; mt < 16; mt++) acc[mt] = (f32x4v){0.f, 0.f, 0.f, 0.f};

#pragma unroll
        for (int kb = 0; kb < 2; kb++) {
            const int ko = kb * 32 + quad * 8;
            bf16x8 bfrag = *(const bf16x8*)&Wo2T[col * 64 + ko];
#pragma unroll
            for (int mt = 0; mt < 16; mt++) {
                bf16x8 afrag = *(const bf16x8*)&A2[(mt * 16 + lcol) * 72 + ko];
                acc[mt] = __builtin_amdgcn_mfma_f32_16x16x32_bf16(afrag, bfrag, acc[mt], 0, 0, 0);
            }
        }

#pragma unroll
        for (int mt = 0; mt < 16; mt++) {
#pragma unroll
            for (int reg = 0; reg < 4; reg++) {
                int j = mt * 16 + quad * 4 + reg;
                float hev = acc[mt][reg];
                he_mtx[((size_t)bi * NN + j) * HH + col] = hev;
                A1[j * 72 + col] = f2bf(hev);
            }
        }
    }
    __syncthreads();

    // ---- phase 4: sem logits (thread = j)
    {
        int j = tid;
        const float4* Ws4 = (const float4*)Ws;   // row ch -> 4 heads
        float a0 = bs[0], a1 = bs[1], a2 = bs[2], a3 = bs[3];
#pragma unroll
        for (int c8 = 0; c8 < 64; c8 += 8) {
            bf16x8 hv8 = *(const bf16x8*)&A1[j * 72 + c8];
#pragma unroll
            for (int t = 0; t < 8; t++) {
                float hv = bf2f(hv8[t]);
                float4 wsv = Ws4[c8 + t];
                a0 += hv * wsv.x; a1 += hv * wsv.y;
                a2 += hv * wsv.z; a3 += hv * wsv.w;
            }
        }
        float4 out;
        out.x = a0 > 0.f ? a0 : 2.f * expm1f(0.5f * a0);
        out.y = a1 > 0.f ? a1 : 2.f * expm1f(0.5f * a1);
        out.z = a2 > 0.f ? a2 : 2.f * expm1f(0.5f * a2);
        out.w = a3 > 0.f ? a3 : 2.f * expm1f(0.5f * a3);
        if (i == j) { out.x -= 1e5f; out.y -= 1e5f; out.z -= 1e5f; out.w -= 1e5f; }
        ((float4*)sem_logit)[(size_t)bi * NN + j] = out;
    }
}

// ---------------------------------------------------------------------------
// K2: the three softmaxes over j (round-1 verified).
// ---------------------------------------------------------------------------
__device__ __forceinline__ float4 block_max4(float4 v, float4* buf) {
    int tid = threadIdx.x;
    buf[tid] = v;
    __syncthreads();
    for (int s = 128; s > 0; s >>= 1) {
        if (tid < s) {
            float4 o = buf[tid + s], m = buf[tid];
            m.x = fmaxf(m.x, o.x); m.y = fmaxf(m.y, o.y);
            m.z = fmaxf(m.z, o.z); m.w = fmaxf(m.w, o.w);
            buf[tid] = m;
        }
        __syncthreads();
    }
    float4 r = buf[0];
    __syncthreads();
    return r;
}

__device__ __forceinline__ float4 block_sum4(float4 v, float4* buf) {
    int tid = threadIdx.x;
    buf[tid] = v;
    __syncthreads();
    for (int s = 128; s > 0; s >>= 1) {
        if (tid < s) {
            float4 o = buf[tid + s], m = buf[tid];
            m.x += o.x; m.y += o.y; m.z += o.z; m.w += o.w;
            buf[tid] = m;
        }
        __syncthreads();
    }
    float4 r = buf[0];
    __syncthreads();
    return r;
}

__global__ __launch_bounds__(256) void k2_attn(
    const float* __restrict__ norm_g, const float* __restrict__ sem_logit,
    const float* __restrict__ log_gamma, float* __restrict__ comb_att)
{
    __shared__ float4 buf[256];
    const int bi = blockIdx.x;
    const int i = bi & 255;
    const int j = threadIdx.x;
    const size_t base = (size_t)bi * NN + j;

    float g0 = __expf(log_gamma[0]);
    float g1 = __expf(log_gamma[1]);
    float g2 = __expf(log_gamma[2]);
    float g3 = __expf(log_gamma[3]);

    float nrm = norm_g[base];
    float pen = (j == i) ? 1e5f : 0.f;
    float nl = -(nrm + pen);
    float4 el = make_float4(nl * g0, nl * g1, nl * g2, nl * g3);
    float4 sl = ((const float4*)sem_logit)[base];

    float4 m = block_max4(el, buf);
    float4 ev = make_float4(__expf(el.x - m.x), __expf(el.y - m.y),
                            __expf(el.z - m.z), __expf(el.w - m.w));
    float4 sum = block_sum4(ev, buf);
    float4 eucl = make_float4(ev.x / sum.x, ev.y / sum.y, ev.z / sum.z, ev.w / sum.w);

    m = block_max4(sl, buf);
    float4 sv = make_float4(__expf(sl.x - m.x), __expf(sl.y - m.y),
                            __expf(sl.z - m.z), __expf(sl.w - m.w));
    sum = block_sum4(sv, buf);
    float4 sem = make_float4(sv.x / sum.x, sv.y / sum.y, sv.z / sum.z, sv.w / sum.w);

    float4 cl = make_float4(eucl.x * sem.x, eucl.y * sem.y, eucl.z * sem.z, eucl.w * sem.w);
    m = block_max4(cl, buf);
    float4 cv = make_float4(__expf(cl.x - m.x), __expf(cl.y - m.y),
                            __expf(cl.z - m.z), __expf(cl.w - m.w));
    sum = block_sum4(cv, buf);
    float4 ca = make_float4(cv.x / sum.x, cv.y / sum.y, cv.z / sum.z, cv.w / sum.w);

    ((float4*)comb_att)[base] = ca;
}

// ---------------------------------------------------------------------------
// K3: bf16 MFMA spatial attention, vectorized coalesced staging.
// Staging: wave w stages rows {w, w+4, ..., w+60} of the 64-j tile.
//   lane l: hv = he_mtx[j][l] (coalesced 256B/wave), av = comb_att[j] (bcast
//   float4), produces columns 4l..4l+3 as one ushort4 (b64 write).
// h_e partials per wave in registers, cross-wave LDS reduce at end.
// MFMA loop and epilogue unchanged (round-4/5 verified).
// ---------------------------------------------------------------------------
__global__ __launch_bounds__(256) void k3_spatial(
    const float* __restrict__ he_mtx, const float* __restrict__ comb_att,
    const float* __restrict__ x, const float* __restrict__ norm_g,
    const unsigned short* __restrict__ WxT, const float* __restrict__ Wv_mix,
    float* __restrict__ h_e, float* __restrict__ comb_norm,
    float* __restrict__ delta_v)
{
    __shared__ unsigned short hea[64 * 264];   // 33 KB
    __shared__ float4 xds[64];                 // 1 KB
    __shared__ float red_he[4][CC];            // 4 KB cross-wave h_e partials
    __shared__ float dvbuf[4][3];

    const int tid = threadIdx.x;
    const int l = tid & 63;
    const int w = tid >> 6;
    const int lrow = l >> 4;        // quad 0..3
    const int lcol = l & 15;
    const int wcol = w * 64;
    const int bi = blockIdx.x;
    const int b = bi >> 8;
    const int i = bi & 255;

    const float* xb = x + (size_t)b * NN * 3;
    const float xi0 = xb[i * 3 + 0], xi1 = xb[i * 3 + 1], xi2 = xb[i * 3 + 2];

    float wv_l[4];
#pragma unroll
    for (int nt = 0; nt < 4; nt++) wv_l[nt] = Wv_mix[wcol + nt * 16 + lcol];

    float cs[4][3] = {{0.f,0.f,0.f},{0.f,0.f,0.f},{0.f,0.f,0.f},{0.f,0.f,0.f}};
    float dv[3] = {0.f, 0.f, 0.f};
    float he4[4] = {0.f, 0.f, 0.f, 0.f};   // cols 4l..4l+3, this wave's j's

    for (int pass = 0; pass < 4; pass++) {
        const int jt = pass * 64;

        // ---- staging: 16 coalesced rows per wave
#pragma unroll 4
        for (int jj = 0; jj < 16; jj++) {
            const int row = jj * 4 + w;
            const int j = jt + row;
            float hv = he_mtx[((size_t)bi * NN + j) * HH + l];
            float4 av = ((const float4*)comb_att)[(size_t)bi * NN + j];
            float v0 = hv * av.x, v1 = hv * av.y, v2 = hv * av.z, v3 = hv * av.w;
            he4[0] += v0; he4[1] += v1; he4[2] += v2; he4[3] += v3;
            ushort4 pk = make_ushort4(f2bf(v0), f2bf(v1), f2bf(v2), f2bf(v3));
            *(ushort4*)&hea[row * 264 + 4 * l] = pk;
        }
        if (tid < 64) {
            int j = jt + tid;
            float nrm = norm_g[(size_t)bi * NN + j];
            float inv = 1.f / (nrm + 1e-5f);
            xds[tid] = make_float4((xb[j * 3 + 0] - xi0) * inv,
                                   (xb[j * 3 + 1] - xi1) * inv,
                                   (xb[j * 3 + 2] - xi2) * inv, 0.f);
        }
        __syncthreads();

        // ---- MFMA: [64 j] x [256 k] @ WxT -> wave's 64 cols
        f32x4v acc[4][4];
#pragma unroll
        for (int mt = 0; mt < 4; mt++)
#pragma unroll
            for (int nt = 0; nt < 4; nt++)
                acc[mt][nt] = (f32x4v){0.f, 0.f, 0.f, 0.f};

        for (int kb = 0; kb < 8; kb++) {
            const int ko = kb * 32 + lrow * 8;
            bf16x8 af[4], bf[4];
#pragma unroll
            for (int mt = 0; mt < 4; mt++)
                af[mt] = *(const bf16x8*)&hea[(mt * 16 + lcol) * 264 + ko];
#pragma unroll
            for (int nt = 0; nt < 4; nt++)
                bf[nt] = *(const bf16x8*)&WxT[(size_t)(wcol + nt * 16 + lcol) * 256 + ko];
#pragma unroll
            for (int mt = 0; mt < 4; mt++)
#pragma unroll
                for (int nt = 0; nt < 4; nt++)
                    acc[mt][nt] = __builtin_amdgcn_mfma_f32_16x16x32_bf16(
                        af[mt], bf[nt], acc[mt][nt], 0, 0, 0);
        }

        // ---- epilogue: tanh + cs/dv accumulation
#pragma unroll
        for (int mt = 0; mt < 4; mt++) {
#pragma unroll
            for (int reg = 0; reg < 4; reg++) {
                int row = mt * 16 + lrow * 4 + reg;
                float4 xv = xds[row];
#pragma unroll
                for (int nt = 0; nt < 4; nt++) {
                    float coeff = tanh_fast(acc[mt][nt][reg]);
                    float cw = coeff * wv_l[nt];
                    cs[nt][0] += xv.x * coeff; cs[nt][1] += xv.y * coeff; cs[nt][2] += xv.z * coeff;
                    dv[0] += xv.x * cw; dv[1] += xv.y * cw; dv[2] += xv.z * cw;
                }
            }
        }
        __syncthreads();   // protect hea/xds before next pass staging
    }

    // ---- h_e: cross-wave reduce of per-wave column partials
    *(float4*)&red_he[w][4 * l] = make_float4(he4[0], he4[1], he4[2], he4[3]);
    __syncthreads();
    {
        float hv = red_he[0][tid] + red_he[1][tid] + red_he[2][tid] + red_he[3][tid];
        h_e[(size_t)bi * CC + tid] = hv;
    }

    // ---- comb_norm: reduce cs over the 4 row-group lanes (xor 16, 32)
#pragma unroll
    for (int nt = 0; nt < 4; nt++)
#pragma unroll
        for (int t = 0; t < 3; t++) {
            cs[nt][t] += __shfl_xor(cs[nt][t], 16, 64);
            cs[nt][t] += __shfl_xor(cs[nt][t], 32, 64);
        }
    if (lrow == 0) {
        const float invn = 1.f / (float)NN;
#pragma unroll
        for (int nt = 0; nt < 4; nt++) {
            int colx = wcol + nt * 16 + lcol;
            float m0 = cs[nt][0] * invn, m1 = cs[nt][1] * invn, m2 = cs[nt][2] * invn;
            comb_norm[(size_t)bi * CC + colx] = m0 * m0 + m1 * m1 + m2 * m2;
        }
    }

    // ---- delta_v: full wave reduce then cross-wave via LDS
#pragma unroll
    for (int t = 0; t < 3; t++)
#pragma unroll
        for (int off = 32; off >= 1; off >>= 1)
            dv[t] += __shfl_xor(dv[t], off, 64);
    if (l == 0) {
        dvbuf[w][0] = dv[0]; dvbuf[w][1] = dv[1]; dvbuf[w][2] = dv[2];
    }
    __syncthreads();
    if (tid < 3) {
        float ssum = dvbuf[0][tid] + dvbuf[1][tid] + dvbuf[2][tid] + dvbuf[3][tid];
        delta_v[(size_t)bi * 3 + tid] = ssum * (1.f / (float)NN);
    }
}

// ---------------------------------------------------------------------------
// K4: node MLPs + velocity/position update (round-1 verified).
// ---------------------------------------------------------------------------
__global__ __launch_bounds__(64) void k4_node(
    const float* __restrict__ h, const float* __restrict__ x, const float* __restrict__ v,
    const float* __restrict__ h_e, const float* __restrict__ comb_norm,
    const float* __restrict__ delta_v,
    const float* __restrict__ Wp1, const float* __restrict__ bp1,
    const float* __restrict__ Wp2, const float* __restrict__ bp2,
    const float* __restrict__ Wn1, const float* __restrict__ bn1,
    const float* __restrict__ Wn2, const float* __restrict__ bn2,
    const float* __restrict__ Wvel1, const float* __restrict__ bvel1,
    const float* __restrict__ Wvel2,
    float* __restrict__ out)
{
    __shared__ float cn[CC];
    __shared__ float inb[FF + CC + HH];
    __shared__ float tmp[HH];
    __shared__ float hn[HH];

    const int bi = blockIdx.x;
    const int t = threadIdx.x;

#pragma unroll
    for (int r = 0; r < 4; r++) {
        cn[r * 64 + t] = comb_norm[(size_t)bi * CC + r * 64 + t];
        inb[FF + r * 64 + t] = h_e[(size_t)bi * CC + r * 64 + t];
    }
    inb[t] = h[(size_t)bi * FF + t];
    __syncthreads();

    float acc = bp1[t];
#pragma unroll 8
    for (int k = 0; k < CC; k++) acc += cn[k] * Wp1[k * HH + t];
    tmp[t] = siluf(acc);
    __syncthreads();
    acc = bp2[t];
#pragma unroll 8
    for (int k = 0; k < HH; k++) acc += tmp[k] * Wp2[k * HH + t];
    inb[FF + CC + t] = siluf(acc);
    __syncthreads();

    acc = bn1[t];
#pragma unroll 8
    for (int k = 0; k < FF + CC + HH; k++) acc += inb[k] * Wn1[k * HH + t];
    float n1v = siluf(acc);
    __syncthreads();
    tmp[t] = n1v;
    __syncthreads();
    acc = bn2[t];
#pragma unroll 8
    for (int k = 0; k < HH; k++) acc += tmp[k] * Wn2[k * FF + t];
    float hnew = inb[t] + siluf(acc);
    hn[t] = hnew;
    out[(size_t)bi * FF + t] = hnew;
    __syncthreads();

    acc = bvel1[t];
#pragma unroll 8
    for (int k = 0; k < HH; k++) acc += hn[k] * Wvel1[k * HH + t];
    float val = siluf(acc) * Wvel2[t];
#pragma unroll
    for (int off = 32; off >= 1; off >>= 1) val += __shfl_xor(val, off, 64);
    float vscale = 2.f * sigmoidf_(val);

    if (t < 3) {
        float vv = v[(size_t)bi * 3 + t];
        float vn = delta_v[(size_t)bi * 3 + t] + vscale * vv;
        out[32768 + (size_t)bi * 3 + t] = x[(size_t)bi * 3 + t] + vn;  // x_new
        out[34304 + (size_t)bi * 3 + t] = vn;                           // v_new
    }
}

// ---------------------------------------------------------------------------
extern "C" void kernel_launch(void* const* d_in, const int* in_sizes, int n_in,
                              void* d_out, int out_size, void* d_ws, size_t ws_size,
                              hipStream_t stream)
{
    const float* h        = (const float*)d_in[0];
    const float* x        = (const float*)d_in[1];
    const float* v        = (const float*)d_in[2];
    const float* means    = (const float*)d_in[3];
    const float* betas    = (const float*)d_in[4];
    const float* W_in     = (const float*)d_in[5];
    const float* b_in     = (const float*)d_in[6];
    const float* W_o1     = (const float*)d_in[7];
    const float* b_o1     = (const float*)d_in[8];
    const float* W_o2     = (const float*)d_in[9];
    const float* b_o2     = (const float*)d_in[10];
    const float* Ws       = (const float*)d_in[11];
    const float* bs       = (const float*)d_in[12];
    const float* log_gamma= (const float*)d_in[13];
    const float* Wx       = (const float*)d_in[14];
    const float* Wp1      = (const float*)d_in[15];
    const float* bp1      = (const float*)d_in[16];
    const float* Wp2      = (const float*)d_in[17];
    const float* bp2      = (const float*)d_in[18];
    const float* Wn1      = (const float*)d_in[19];
    const float* bn1      = (const float*)d_in[20];
    const float* Wn2      = (const float*)d_in[21];
    const float* bn2      = (const float*)d_in[22];
    const float* Wv_mix   = (const float*)d_in[23];
    const float* Wvel1    = (const float*)d_in[24];
    const float* bvel1    = (const float*)d_in[25];
    const float* Wvel2    = (const float*)d_in[26];

    float* ws = (float*)d_ws;
    float* norm_g    = ws;                 // 131072
    float* he_mtx    = ws + 131072;        // 8388608
    float* sem_logit = ws + 8519680;       // 524288 (WxT bf16 aliased after k2)
    float* comb_att  = ws + 9043968;       // 524288 (UVPQ + Wo1T/Wo2T aliased pre-k2)
    float* h_e       = ws + 9568256;       // 131072
    float* comb_norm = ws + 9699328;       // 131072
    float* delta_v   = ws + 9830400;       // 1536

    // Pre-k2 aliases in the comb_att region (dead until k2 writes it):
    float* U = comb_att;                   // 512*64
    float* V = comb_att + 32768;
    float* P = comb_att + 65536;
    float* Q = comb_att + 98304;
    unsigned short* Wo1T = (unsigned short*)(comb_att + 131072);  // 4096 shorts
    unsigned short* Wo2T = (unsigned short*)(comb_att + 133120);  // 4096 shorts

    // WxT bf16 aliases sem_logit (dead after k2; k0b runs after k2).
    unsigned short* WxT = (unsigned short*)sem_logit;

    k0_node_pre<<<dim3(BN), dim3(64), 0, stream>>>(
        h, W_in, b_in, W_o1, b_o1, U, V, P, Q);

    k0c_wtrans<<<dim3(16), dim3(256), 0, stream>>>(W_o1, W_o2, Wo1T, Wo2T);

    k1_edge_mfma<<<dim3(BN), dim3(256), 0, stream>>>(
        x, means, betas, U, V, P, Q, Wo1T, Wo2T, Ws, bs,
        he_mtx, sem_logit, norm_g);

    k2_attn<<<dim3(BN), dim3(256), 0, stream>>>(norm_g, sem_logit, log_gamma, comb_att);

    k0b_wxt<<<dim3(256), dim3(256), 0, stream>>>(Wx, WxT);

    k3_spatial<<<dim3(BN), dim3(256), 0, stream>>>(
        he_mtx, comb_att, x, norm_g, WxT, Wv_mix, h_e, comb_norm, delta_v);

    k4_node<<<dim3(BN), dim3(64), 0, stream>>>(
        h, x, v, h_e, comb_norm, delta_v,
        Wp1, bp1, Wp2, bp2, Wn1, bn1, Wn2, bn2, Wvel1, bvel1, Wvel2,
        (float*)d_out);
}